// Round 21
// baseline (295.617 us; speedup 1.0000x reference)
//
#include <hip/hip_runtime.h>
#include <hip/hip_bf16.h>
#include <cstdint>
#include <cstddef>

#define DI __device__ __forceinline__

// ---------- constants ----------
#define NN 500
#define NQ 2000           // B*N
#define GTOT 32768        // G*TOTAL
#define LN_EPS 1e-5f

typedef __attribute__((ext_vector_type(8))) short short8v;
typedef __attribute__((ext_vector_type(4))) float f32x4;
typedef __attribute__((ext_vector_type(2))) float f32x2;
typedef const __attribute__((address_space(1))) void* gp1_t;
typedef __attribute__((address_space(3))) void* lp3_t;

DI unsigned short f2bf(float f){
  unsigned u = __float_as_uint(f);
  return (unsigned short)((u + 0x7fffu + ((u>>16)&1u)) >> 16);
}
DI float bf2f(unsigned short s){ return __uint_as_float(((unsigned)s)<<16); }

DI ushort4 cvt4(float4 a){
  ushort4 r; r.x=f2bf(a.x); r.y=f2bf(a.y); r.z=f2bf(a.z); r.w=f2bf(a.w); return r;
}

// block-wide (256 thr = 4 waves) sum of s, s2
DI void bred256(float& s, float& s2, float* red, int tid){
  #pragma unroll
  for(int off=32; off; off>>=1){
    s  += __shfl_xor(s,  off, 64);
    s2 += __shfl_xor(s2, off, 64);
  }
  int w = tid>>6;
  if((tid&63)==0){ red[w*2]=s; red[w*2+1]=s2; }
  __syncthreads();
  s  = red[0]+red[2]+red[4]+red[6];
  s2 = red[1]+red[3]+red[5]+red[7];
  __syncthreads();
}

// ---------- K1: offset GEMM + sample coords + level softmax (384 thr) ----------
__global__ __launch_bounds__(384) void k_off(const float* __restrict__ qf,
    const float* __restrict__ xyzr, const float* __restrict__ w_off,
    const float* __restrict__ b_off, float2* __restrict__ xyb, float4* __restrict__ lwb){
  __shared__ float qs[8][256];
  __shared__ float os[8][384];
  int q0 = blockIdx.x*8, tid = threadIdx.x;
  for(int idx=tid; idx<2048; idx+=384){
    int qq = idx>>8, k = idx&255;
    qs[qq][k] = qf[(size_t)(q0+qq)*256 + k];
  }
  __syncthreads();
  {
    int j = tid;
    float acc[8];
    #pragma unroll
    for(int i=0;i<8;i++) acc[i]=0.f;
    for(int k=0;k<256;k++){
      float w = w_off[(size_t)k*384 + j];
      #pragma unroll
      for(int qq=0;qq<8;qq++) acc[qq] += qs[qq][k]*w;
    }
    float bb = b_off[j];
    #pragma unroll
    for(int qq=0;qq<8;qq++) os[qq][j] = acc[qq] + bb;
  }
  __syncthreads();
  for(int idx=tid; idx<1024; idx+=384){
    int qq = idx>>7, gp = idx&127;
    int q = q0+qq;
    float4 xr = *(const float4*)&xyzr[(size_t)q*4];
    float rw = exp2f(xr.z - 0.5f*xr.w);
    float rh = exp2f(xr.z + 0.5f*xr.w);
    float sx = xr.x + os[qq][gp*3+0]*rw;
    float sy = xr.y + os[qq][gp*3+1]*rh;
    float lvl = xr.z + os[qq][gp*3+2] - 3.0f;
    float d0=lvl, d1=lvl-1.f, d2=lvl-2.f, d3=lvl-3.f;
    float e0=-0.5f*d0*d0, e1=-0.5f*d1*d1, e2=-0.5f*d2*d2, e3=-0.5f*d3*d3;
    float m = fmaxf(fmaxf(e0,e1),fmaxf(e2,e3));
    float x0=expf(e0-m), x1=expf(e1-m), x2=expf(e2-m), x3=expf(e3-m);
    float inv = 1.f/(x0+x1+x2+x3);
    xyb[(size_t)q*128+gp] = make_float2(sx,sy);
    lwb[(size_t)q*128+gp] = make_float4(x0*inv, x1*inv, x2*inv, x3*inv);
  }
}

// ---------- K-prep2: fused transposes + cvtqf ----------
__global__ __launch_bounds__(256) void k_prep2(
    const float* __restrict__ f0, const float* __restrict__ f1,
    const float* __restrict__ f2, const float* __restrict__ f3,
    const float* __restrict__ qf, const float* __restrict__ w_pg,
    const float* __restrict__ w_out, unsigned short* __restrict__ featT,
    unsigned short* __restrict__ qfb, unsigned short* __restrict__ wpgT,
    unsigned short* __restrict__ woutT){
  __shared__ unsigned short tile[64*68];
  int bid = blockIdx.x, tid = threadIdx.x;

  if(bid < 4096){
    const float* src; unsigned short* dst; int R, C, lb;
    if(bid < 2048){ src=w_pg;  dst=wpgT;  R=256;  C=GTOT; lb=bid; }
    else          { src=w_out; dst=woutT; R=GTOT; C=256;  lb=bid-2048; }
    int ctiles = C >> 6;
    int rt = lb / ctiles, ct = lb % ctiles;
    int r0 = rt<<6, c0 = ct<<6;
    #pragma unroll
    for(int i=0;i<4;i++){
      int idx = tid + i*256;
      int r = idx >> 4, c4 = (idx & 15)*4;
      float4 v = *(const float4*)(src + (size_t)(r0+r)*C + c0 + c4);
      *(ushort4*)(tile + r*68 + c4) = cvt4(v);
    }
    __syncthreads();
    #pragma unroll
    for(int i=0;i<4;i++){
      int idx = tid + i*256;
      int cc = idx >> 4, r4 = (idx & 15)*4;
      ushort4 v;
      v.x = tile[(r4+0)*68 + cc];
      v.y = tile[(r4+1)*68 + cc];
      v.z = tile[(r4+2)*68 + cc];
      v.w = tile[(r4+3)*68 + cc];
      *(ushort4*)(dst + (size_t)(c0+cc)*R + r0 + r4) = v;
    }
  } else if(bid < 9440){
    const float* src; unsigned short* dst; int HW, nb, lb;
    int fb = bid - 4096;
    if(fb < 4000){ src=f0; dst=featT;            HW=16000; nb=250; lb=fb; }
    else if(fb < 5008){ src=f1; dst=featT+16384000; HW=4000; nb=63; lb=fb-4000; }
    else if(fb < 5264){ src=f2; dst=featT+20480000; HW=1000; nb=16; lb=fb-5008; }
    else { src=f3; dst=featT+21504000; HW=260; nb=5; lb=fb-5264; }
    int bg = lb / nb, hb = lb % nb;
    int b = bg >> 2, g = bg & 3;
    const float* s = src + ((size_t)(b*256 + g*64))*HW + hb*64;
    unsigned short* d = dst + (size_t)bg*HW*64 + (size_t)hb*64*64;
    int rem = HW - hb*64;
    #pragma unroll
    for(int i=0;i<4;i++){
      int idx = tid + i*256;
      int c = idx >> 4, h4 = (idx & 15)*4;
      if(h4 < rem){
        float4 v = *(const float4*)(s + (size_t)c*HW + h4);
        *(ushort4*)(tile + c*68 + h4) = cvt4(v);
      }
    }
    __syncthreads();
    #pragma unroll
    for(int i=0;i<4;i++){
      int idx = tid + i*256;
      int hw = idx >> 4, c4 = (idx & 15)*4;
      if(hw < rem){
        ushort4 v;
        v.x = tile[(c4+0)*68 + hw];
        v.y = tile[(c4+1)*68 + hw];
        v.z = tile[(c4+2)*68 + hw];
        v.w = tile[(c4+3)*68 + hw];
        *(ushort4*)(d + (size_t)hw*64 + c4) = v;
      }
    }
  } else {
    int idx = (bid-9440)*256 + tid;
    size_t base = (size_t)idx*8;
    int row = idx >> 5;
    ushort4 lo, hi;
    if(row < NQ){
      float4 a = *(const float4*)(qf + base);
      float4 b = *(const float4*)(qf + base + 4);
      lo = cvt4(a); hi = cvt4(b);
    } else {
      lo.x=lo.y=lo.z=lo.w=0; hi.x=hi.y=hi.z=hi.w=0;
    }
    *(ushort4*)(qfb + base) = lo;
    *(ushort4*)(qfb + base + 4) = hi;
  }
}

// ---------- MFMA helpers ----------
DI f32x4 mfma16(short8v a, short8v b, f32x4 c){
  return __builtin_amdgcn_mfma_f32_16x16x32_bf16(a, b, c, 0, 0, 0);
}

// swizzle for [*][32]-short tiles: 16B chunk c XOR row bits -> bank-balanced b128 reads
DI int swz32(int c, int r){ return c ^ (r&3) ^ ((r>>2)&3); }

// stage a 128x32 bf16 tile into linear LDS via global_load_lds, source pre-swizzled.
DI void stageG32(const unsigned short* __restrict__ g, size_t row0, size_t ldk,
                 size_t k0, unsigned short* lds, int tid){
  int wv = tid>>6;
  #pragma unroll
  for(int i=0;i<2;i++){
    int e = i*256 + tid;          // 16B-chunk index 0..511
    int r = e>>2, c = e&3;
    int cs = swz32(c, r);
    const unsigned short* gp = g + (row0 + (size_t)r)*ldk + k0 + (size_t)cs*8;
    unsigned short* lp = lds + (size_t)(i*256 + wv*64)*8;   // wave-uniform base
    __builtin_amdgcn_global_load_lds((gp1_t)(const void*)gp, (lp3_t)(void*)lp, 16, 0, 0);
  }
}

// read one fragment (row, k-chunk q4) from swizzled [*][32] tile
DI short8v frag32(const unsigned short* lds, int row, int q4){
  return *(const short8v*)(lds + (size_t)row*32 + (size_t)swz32(q4, row)*8);
}

// one BK=32 step for 128x128 tile: 4 A-frags, 4 B-frags, 16 MFMA
DI void mma32(const unsigned short* lsA, const unsigned short* lsB,
              int wm, int wn, int lane, f32x4 acc[4][4]){
  int r15 = lane&15, q4 = lane>>4;
  short8v a[4], b[4];
  #pragma unroll
  for(int i=0;i<4;i++){
    a[i] = frag32(lsA, wm*64 + i*16 + r15, q4);
    b[i] = frag32(lsB, wn*64 + i*16 + r15, q4);
  }
  #pragma unroll
  for(int mi=0;mi<4;mi++)
    #pragma unroll
    for(int ni=0;ni<4;ni++)
      acc[mi][ni] = mfma16(a[mi], b[ni], acc[mi][ni]);
}

// XCD-affinity remap: consecutive logical blocks land on one XCD (nwg % 8 == 0).
DI int xcd_remap(int bid, int nwg){
  return ((bid & 7) * (nwg >> 3)) + (bid >> 3);
}

// ---------- K2: params GEMM via MFMA: par = qfb @ wpgT^T + b_pg ----------
__global__ __launch_bounds__(256, 4) void k_pgemm_mfma(const unsigned short* __restrict__ qfb,
    const unsigned short* __restrict__ wpgT, const float* __restrict__ b_pg,
    unsigned short* __restrict__ par, int qbase, int qlim, int mtiles){
  __shared__ unsigned short pool[16384];     // 32 KB
  int bid = xcd_remap(blockIdx.x, gridDim.x);
  int mt = bid % mtiles, nt = bid / mtiles;
  size_t m0 = (size_t)mt*128, n0 = (size_t)nt*128;
  int tid = threadIdx.x, lane = tid&63, wv = tid>>6;
  int wm = wv>>1, wn = wv&1;
  int r15 = lane&15, q4 = lane>>4;
  f32x4 acc[4][4] = {};
  stageG32(qfb,  qbase+m0, 256, 0, pool, tid);
  stageG32(wpgT, n0,       256, 0, pool + 8192, tid);
  __syncthreads();
  #pragma unroll
  for(int t=0; t<8; t++){
    int co = (t&1)*4096;
    if(t<7){
      int no = ((t&1)^1)*4096;
      stageG32(qfb,  qbase+m0, 256, (size_t)(t+1)*32, pool + no, tid);
      stageG32(wpgT, n0,       256, (size_t)(t+1)*32, pool + 8192 + no, tid);
    }
    mma32(pool + co, pool + 8192 + co, wm, wn, lane, acc);
    __syncthreads();
  }
  // epilogue: stage bf16 result in LDS [128][72], store full 128B rows, two col-halves
  unsigned short* es = pool;
  #pragma unroll
  for(int h=0; h<2; ++h){
    if(h) __syncthreads();
    if(wn == h){
      #pragma unroll
      for(int ni=0; ni<4; ni++){
        float bias = b_pg[(int)n0 + wn*64 + ni*16 + r15];
        #pragma unroll
        for(int mi=0; mi<4; mi++)
          #pragma unroll
          for(int j=0; j<4; j++){
            int row = wm*64 + mi*16 + q4*4 + j;
            es[row*72 + ni*16 + r15] = f2bf(acc[mi][ni][j] + bias);
          }
      }
    }
    __syncthreads();
    #pragma unroll
    for(int i=0;i<4;i++){
      int e = i*256 + tid;              // 1024 chunks of 8 shorts
      int row = e>>3, c8 = (e&7)*8;
      int rl = (int)m0 + row;
      if(qbase + rl < qlim){
        uint4 v = *(const uint4*)(es + row*72 + c8);
        *(uint4*)&par[(size_t)rl*GTOT + n0 + h*64 + c8] = v;
      }
    }
  }
}

// ---------- K4: final GEMM via MFMA, 128x128 tiles, K-split x kspl -> f32 partials ----------
__global__ __launch_bounds__(256, 4) void k_fgemm_mfma(const unsigned short* __restrict__ Ag,
    const unsigned short* __restrict__ woutT, float* __restrict__ part,
    int qbase, int qlim, int mtiles, int kspl){
  __shared__ unsigned short pool[16384];
  int bid = xcd_remap(blockIdx.x, gridDim.x);
  int nt = bid & 1;
  int r2 = bid >> 1;
  int mt = r2 % mtiles, ks = r2 / mtiles;
  size_t m0 = (size_t)mt*128, n0 = (size_t)nt*128;
  int tid = threadIdx.x, lane = tid&63, wv = tid>>6;
  int wm = wv>>1, wn = wv&1;
  f32x4 acc[4][4] = {};
  int klen = GTOT / kspl;
  size_t kbase = (size_t)ks*klen;
  int NT = klen >> 5;
  stageG32(Ag,    m0, GTOT, kbase, pool, tid);
  stageG32(woutT, n0, GTOT, kbase, pool + 8192, tid);
  __syncthreads();
  for(int t=0; t<NT; t++){
    int co = (t&1)*4096;
    if(t+1<NT){
      int no = ((t&1)^1)*4096;
      stageG32(Ag,    m0, GTOT, kbase + (size_t)(t+1)*32, pool + no, tid);
      stageG32(woutT, n0, GTOT, kbase + (size_t)(t+1)*32, pool + 8192 + no, tid);
    }
    mma32(pool + co, pool + 8192 + co, wm, wn, lane, acc);
    __syncthreads();
  }
  float* pp = part + (size_t)ks*NQ*256;
  int r15 = lane&15, q4 = lane>>4;
  #pragma unroll
  for(int mi=0; mi<4; mi++){
    #pragma unroll
    for(int j=0; j<4; j++){
      int rl = (int)m0 + wm*64 + mi*16 + q4*4 + j;
      int q = qbase + rl;
      if(q < qlim){
        #pragma unroll
        for(int ni=0; ni<4; ni++){
          int col = (int)n0 + wn*64 + ni*16 + r15;
          pp[(size_t)q*256 + col] = acc[mi][ni][j];
        }
      }
    }
  }
}

// ---------- K3: sampling + M/S mixing via MFMA + two group-LN+relu -> out2 bf16 ----------
// Merged pool 26624 B -> 6 blocks/CU. Layout (byte offsets):
//   offW [0,4096)  xs[32][72] [4096,8704)  Ms[64][68] [8704,17408)  Ss[128][36] [17408,26624)
//   o1t[64][40] aliases [0,5120): written in Phase B AFTER bred256 barrier; offW dead after
//     Phase A, xs reads complete before Phase-B bred256 barrier.
//   o2s[128][72] aliases [0,18432): written in Phase C AFTER bred256 barrier; o1t/xs/Ms and
//     Ss-prefix reads all complete before that barrier.
__global__ __launch_bounds__(256) void k_mix(const unsigned short* __restrict__ featT,
    const float2* __restrict__ xyb, const float4* __restrict__ lwb,
    const unsigned short* __restrict__ par, unsigned short* __restrict__ out2,
    int qbase){
  __shared__ __align__(16) char pool[26624];
  __shared__ float red[8];
  float* offW = (float*)pool;
  unsigned short* xs  = (unsigned short*)(pool + 4096);
  unsigned short* Ms  = (unsigned short*)(pool + 8704);
  unsigned short* Ss  = (unsigned short*)(pool + 17408);
  unsigned short* o1t = (unsigned short*)pool;   // alias [0,5120)
  unsigned short* o2s = (unsigned short*)pool;   // alias [0,18432)

  int lq = blockIdx.x >> 2, g = blockIdx.x & 3;
  int q = qbase + lq;
  int b = q / NN;
  int bg = b*4 + g;
  int tid = threadIdx.x;
  int lane = tid & 63, wv = tid >> 6;

  const int HH[4] = {100,50,25,13};
  const int WW[4] = {160,80,40,20};
  const float IS[4] = {0.125f, 0.0625f, 0.03125f, 0.015625f};
  const int LO[4] = {0, 16384000, 20480000, 21504000};

  const unsigned short* pb = par + (size_t)lq*GTOT + (size_t)g*8192;
  uint4 mraw0 = *(const uint4*)(pb + tid*8);
  uint4 mraw1 = *(const uint4*)(pb + 2048 + tid*8);
  uint4 sraw0 = *(const uint4*)(pb + 4096 + tid*8);
  uint4 sraw1 = *(const uint4*)(pb + 6144 + tid*8);

  if(tid < 128){
    int p = tid >> 2, l = tid & 3;
    int pi = q*128 + g*32 + p;
    float2 xy = xyb[pi];
    float lw4 = ((const float*)lwb)[(size_t)pi*4 + l];
    int H = HH[l], W = WW[l];
    float px = xy.x*IS[l] - 0.5f;
    float py = xy.y*IS[l] - 0.5f;
    float xf = floorf(px), yf = floorf(py);
    float wx = px - xf, wy = py - yf;
    int x0 = (int)xf, y0 = (int)yf;
    int x1 = x0 + 1, y1 = y0 + 1;
    bool vx0 = (x0>=0)&&(x0<W), vx1 = (x1>=0)&&(x1<W);
    bool vy0 = (y0>=0)&&(y0<H), vy1 = (y1>=0)&&(y1<H);
    int x0c = min(max(x0,0),W-1), x1c = min(max(x1,0),W-1);
    int y0c = min(max(y0,0),H-1), y1c = min(max(y1,0),H-1);
    int baseB = (LO[l] + bg*H*W*64) * 2;      // BYTE offset base
    float* e = offW + tid*8;
    e[0] = __int_as_float(baseB + (y0c*W + x0c)*128);
    e[1] = __int_as_float(baseB + (y0c*W + x1c)*128);
    e[2] = __int_as_float(baseB + (y1c*W + x0c)*128);
    e[3] = __int_as_float(baseB + (y1c*W + x1c)*128);
    e[4] = (1.f-wx)*(1.f-wy)*lw4*(float)(vx0&&vy0);
    e[5] = wx*(1.f-wy)*lw4*(float)(vx1&&vy0);
    e[6] = (1.f-wx)*wy*lw4*(float)(vx0&&vy1);
    e[7] = wx*wy*lw4*(float)(vx1&&vy1);
  }

  {
    int idx0 = tid*8;
    int c0 = idx0>>6, d0 = idx0&63;
    *(uint2*)(Ms + c0*68 + d0)     = make_uint2(mraw0.x, mraw0.y);
    *(uint2*)(Ms + c0*68 + d0 + 4) = make_uint2(mraw0.z, mraw0.w);
    int idx1 = 2048 + tid*8;
    int c1 = idx1>>6, d1 = idx1&63;
    *(uint2*)(Ms + c1*68 + d1)     = make_uint2(mraw1.x, mraw1.y);
    *(uint2*)(Ms + c1*68 + d1 + 4) = make_uint2(mraw1.z, mraw1.w);
    int o0 = idx0>>5, p0 = idx0&31;
    *(uint2*)(Ss + o0*36 + p0)     = make_uint2(sraw0.x, sraw0.y);
    *(uint2*)(Ss + o0*36 + p0 + 4) = make_uint2(sraw0.z, sraw0.w);
    int o1_ = idx1>>5, p1 = idx1&31;
    *(uint2*)(Ss + o1_*36 + p1)     = make_uint2(sraw1.x, sraw1.y);
    *(uint2*)(Ss + o1_*36 + p1 + 4) = make_uint2(sraw1.z, sraw1.w);
  }
  __syncthreads();

  // Phase A: 4-channel gather. quarter-wave (16 lanes) per p; lane cg = channel quad.
  {
    int pg4 = lane >> 4;           // p within group of 4
    int cg  = lane & 15;           // channel quad: channels cg*4..cg*4+3
    const char* fbB = (const char*)featT + cg*8;
    #pragma unroll
    for(int i=0;i<2;i++){
      int p = wv*8 + i*4 + pg4;
      const float* e = offW + p*32;
      f32x4 acc4 = {0.f, 0.f, 0.f, 0.f};
      #pragma unroll
      for(int l=0;l<4;l++){
        int4  ea = *(const int4*)(e + l*8);
        float4 eb = *(const float4*)(e + l*8 + 4);
        uint2 u00 = *(const uint2*)(fbB + ea.x);
        uint2 u01 = *(const uint2*)(fbB + ea.y);
        uint2 u10 = *(const uint2*)(fbB + ea.z);
        uint2 u11 = *(const uint2*)(fbB + ea.w);
        f32x4 v;
        v[0]=__uint_as_float(u00.x<<16); v[1]=__uint_as_float(u00.x&0xffff0000u);
        v[2]=__uint_as_float(u00.y<<16); v[3]=__uint_as_float(u00.y&0xffff0000u);
        acc4 += v * eb.x;
        v[0]=__uint_as_float(u01.x<<16); v[1]=__uint_as_float(u01.x&0xffff0000u);
        v[2]=__uint_as_float(u01.y<<16); v[3]=__uint_as_float(u01.y&0xffff0000u);
        acc4 += v * eb.y;
        v[0]=__uint_as_float(u10.x<<16); v[1]=__uint_as_float(u10.x&0xffff0000u);
        v[2]=__uint_as_float(u10.y<<16); v[3]=__uint_as_float(u10.y&0xffff0000u);
        acc4 += v * eb.z;
        v[0]=__uint_as_float(u11.x<<16); v[1]=__uint_as_float(u11.x&0xffff0000u);
        v[2]=__uint_as_float(u11.y<<16); v[3]=__uint_as_float(u11.y&0xffff0000u);
        acc4 += v * eb.w;
      }
      unsigned w0 = (unsigned)f2bf(acc4[0]) | ((unsigned)f2bf(acc4[1])<<16);
      unsigned w1 = (unsigned)f2bf(acc4[2]) | ((unsigned)f2bf(acc4[3])<<16);
      *(uint2*)(xs + p*72 + cg*4) = make_uint2(w0, w1);
    }
  }
  __syncthreads();

  int r = lane & 15, q4 = lane >> 4;

  // Phase B: out1 = x(32x64) @ M(64x64)
  {
    short8v af00 = *(const short8v*)(xs + r*72 + q4*8);
    short8v af01 = *(const short8v*)(xs + r*72 + 32 + q4*8);
    short8v af10 = *(const short8v*)(xs + (16+r)*72 + q4*8);
    short8v af11 = *(const short8v*)(xs + (16+r)*72 + 32 + q4*8);
    short8v bm0, bm1;
    #pragma unroll
    for(int j=0;j<8;j++){
      bm0[j] = (short)Ms[(8*q4+j)*68 + wv*16 + r];
      bm1[j] = (short)Ms[(32+8*q4+j)*68 + wv*16 + r];
    }
    f32x4 a0 = {}, a1 = {};
    a0 = mfma16(af00, bm0, a0); a0 = mfma16(af01, bm1, a0);
    a1 = mfma16(af10, bm0, a1); a1 = mfma16(af11, bm1, a1);

    float s = 0.f, s2 = 0.f;
    #pragma unroll
    for(int v=0;v<4;v++){ s += a0[v]+a1[v]; s2 += a0[v]*a0[v] + a1[v]*a1[v]; }
    bred256(s, s2, red, tid);   // barrier: all xs/Ms reads complete before o1t writes below
    float mean = s*(1.f/2048.f);
    float var = s2*(1.f/2048.f) - mean*mean;
    float rs = rsqrtf(var + LN_EPS);
    ushort4 st0, st1;
    {
      float f0;
      f0 = (a0[0]-mean)*rs; st0.x = f2bf(f0>0.f?f0:0.f);
      f0 = (a0[1]-mean)*rs; st0.y = f2bf(f0>0.f?f0:0.f);
      f0 = (a0[2]-mean)*rs; st0.z = f2bf(f0>0.f?f0:0.f);
      f0 = (a0[3]-mean)*rs; st0.w = f2bf(f0>0.f?f0:0.f);
      f0 = (a1[0]-mean)*rs; st1.x = f2bf(f0>0.f?f0:0.f);
      f0 = (a1[1]-mean)*rs; st1.y = f2bf(f0>0.f?f0:0.f);
      f0 = (a1[2]-mean)*rs; st1.z = f2bf(f0>0.f?f0:0.f);
      f0 = (a1[3]-mean)*rs; st1.w = f2bf(f0>0.f?f0:0.f);
    }
    *(ushort4*)(o1t + (wv*16+r)*40 + 4*q4)      = st0;   // p = 4q4..+3 (mi=0)
    *(ushort4*)(o1t + (wv*16+r)*40 + 16 + 4*q4) = st1;   // p = 16+4q4..+3 (mi=1)
  }
  __syncthreads();

  // Phase C: out2 = S(128x32) @ out1(32x64)
  {
    short8v sa0, sa1;
    {
      int row0 = (wv*2+0)*16 + r, row1 = (wv*2+1)*16 + r;
      uint2 a = *(const uint2*)(Ss + row0*36 + q4*8);
      uint2 bq = *(const uint2*)(Ss + row0*36 + q4*8 + 4);
      uint4 t0; t0.x=a.x; t0.y=a.y; t0.z=bq.x; t0.w=bq.y;
      sa0 = *(short8v*)&t0;
      a  = *(const uint2*)(Ss + row1*36 + q4*8);
      bq = *(const uint2*)(Ss + row1*36 + q4*8 + 4);
      uint4 t1; t1.x=a.x; t1.y=a.y; t1.z=bq.x; t1.w=bq.y;
      sa1 = *(short8v*)&t1;
    }
    short8v ov0 = *(const short8v*)(o1t + (r)*40 + q4*8);
    short8v ov1 = *(const short8v*)(o1t + (16+r)*40 + q4*8);
    short8v ov2 = *(const short8v*)(o1t + (32+r)*40 + q4*8);
    short8v ov3 = *(const short8v*)(o1t + (48+r)*40 + q4*8);
    f32x4 c2[2][4] = {};
    c2[0][0] = mfma16(sa0, ov0, c2[0][0]); c2[0][1] = mfma16(sa0, ov1, c2[0][1]);
    c2[0][2] = mfma16(sa0, ov2, c2[0][2]); c2[0][3] = mfma16(sa0, ov3, c2[0][3]);
    c2[1][0] = mfma16(sa1, ov0, c2[1][0]); c2[1][1] = mfma16(sa1, ov1, c2[1][1]);
    c2[1][2] = mfma16(sa1, ov2, c2[1][2]); c2[1][3] = mfma16(sa1, ov3, c2[1][3]);

    float s = 0.f, s2 = 0.f;
    #pragma unroll
    for(int m=0;m<2;m++)
      #pragma unroll
      for(int ni=0;ni<4;ni++)
        #pragma unroll
        for(int v=0;v<4;v++){ float x = c2[m][ni][v]; s += x; s2 += x*x; }
    bred256(s, s2, red, tid);   // barrier: all Ss/o1t reads complete before o2s writes
    float mean = s*(1.f/8192.f);
    float var = s2*(1.f/8192.f) - mean*mean;
    float rs = rsqrtf(var + LN_EPS);
    #pragma unroll
    for(int m=0;m<2;m++)
      #pragma unroll
      for(int ni=0;ni<4;ni++)
        #pragma unroll
        for(int v=0;v<4;v++){
          float x = (c2[m][ni][v]-mean)*rs; x = x>0.f ? x : 0.f;
          int o = (wv*2+m)*16 + 4*q4 + v;
          int d = ni*16 + r;
          o2s[o*72 + d] = f2bf(x);
        }
  }
  __syncthreads();

  // coalesced vectorized store: 128 rows x 64 cols as 1024 uint4 chunks
  unsigned short* og = out2 + (size_t)lq*GTOT + (size_t)g*8192;
  #pragma unroll
  for(int i=0;i<4;i++){
    int e = i*256 + tid;
    int row = e>>3, c8 = (e&7)*8;
    uint4 v = *(const uint4*)(o2s + row*72 + c8);
    *(uint4*)(og + row*64 + c8) = v;
  }
}

// ---------- K5: K-split reduce + bias + residual + LayerNorm ----------
__global__ __launch_bounds__(256) void k_ln(const float* __restrict__ part,
    const float* __restrict__ qf, const float* __restrict__ b_out,
    const float* __restrict__ ln_g, const float* __restrict__ ln_b,
    float* __restrict__ out, int kspl){
  __shared__ float red[8];
  int q = blockIdx.x, j = threadIdx.x;
  float s = qf[(size_t)q*256 + j] + b_out[j];
  for(int ks=0; ks<kspl; ks++) s += part[((size_t)ks*NQ + q)*256 + j];
  float a = s, a2 = s*s;
  bred256(a, a2, red, j);
  float mean = a*(1.f/256.f);
  float var = a2*(1.f/256.f) - mean*mean;
  float rs = rsqrtf(var + LN_EPS);
  out[(size_t)q*256 + j] = (s-mean)*rs*ln_g[j] + ln_b[j];
}

// ---------- launch ----------
extern "C" void kernel_launch(void* const* d_in, const int* in_sizes, int n_in,
                              void* d_out, int out_size, void* d_ws, size_t ws_size,
                              hipStream_t stream) {
  const float* feat0 = (const float*)d_in[0];
  const float* feat1 = (const float*)d_in[1];
  const float* feat2 = (const float*)d_in[2];
  const float* feat3 = (const float*)d_in[3];
  const float* qf    = (const float*)d_in[4];
  const float* xyzr  = (const float*)d_in[5];
  const float* w_off = (const float*)d_in[6];
  const float* b_off = (const float*)d_in[7];
  const float* w_pg  = (const float*)d_in[8];
  const float* b_pg  = (const float*)d_in[9];
  const float* w_out = (const float*)d_in[10];
  const float* b_out = (const float*)d_in[11];
  const float* ln_g  = (const float*)d_in[12];
  const float* ln_b  = (const float*)d_in[13];

  // Layout search (same as rounds 16-20).
  int KSP=0, NC=0, qcount=0, qpad=0;
  size_t oFEAT=0,oXY=0,oLW=0,oPART=0,oQFB=0,oWPGT=0,oWOUT=0,oPAR=0;
  {
    const int a_ksp[2] = {32, 16};
    for(int ci=0; ci<2 && NC==0; ci++){
      size_t o = 0;
      auto al = [&](size_t bytes){ size_t r = o; o = (o + bytes + 255) & ~255ull; return r; };
      size_t tFEAT = al(43540480ull);
      size_t tXY   = al((size_t)NQ*128*8);
      size_t tLW   = al((size_t)NQ*128*16);
      size_t tQFB  = al((size_t)2048*256*2);
      size_t tWPGT = al((size_t)GTOT*256*2);
      size_t partBytes = (size_t)a_ksp[ci]*NQ*256*4;
      if(partBytes > o) o = (partBytes + 255) & ~255ull;   // part aliases [0, ...)
      size_t tWOUT = al((size_t)256*GTOT*2);
      size_t tPAR  = al((size_t)2048*GTOT*2);
      if(o <= ws_size){
        KSP=a_ksp[ci]; NC=1; qcount=NQ; qpad=2048;
        oFEAT=tFEAT; oXY=tXY; oLW=tLW; oPART=0; oQFB=tQFB; oWPGT=tWPGT; oWOUT=tWOUT; oPAR=tPAR;
      }
    }
    const int c_nc[3] = {2,4,8};
    for(int ci=0; ci<3 && NC==0; ci++){
      size_t o = 0;
      auto al = [&](size_t bytes){ size_t r = o; o = (o + bytes + 255) & ~255ull; return r; };
      size_t tFEAT = al(43540480ull);
      size_t tXY   = al((size_t)NQ*128*8);
      size_t tLW   = al((size_t)NQ*128*16);
      size_t tPART = al((size_t)16*NQ*256*4);
      size_t tQFB  = al((size_t)2048*256*2);
      size_t tWPGT = al((size_t)GTOT*256*2);
      size_t tWOUT = al((size_t)256*GTOT*2);
      int qc = NQ / c_nc[ci];
      int qp = (qc + 127) & ~127;
      size_t tPAR = al((size_t)qp*GTOT*2);
      if(o <= ws_size){
        KSP=16; NC=c_nc[ci]; qcount=qc; qpad=qp;
        oFEAT=tFEAT; oXY=tXY; oLW=tLW; oPART=tPART; oQFB=tQFB; oWPGT=tWPGT; oWOUT=tWOUT; oPAR=tPAR;
      }
    }
  }
  if(NC == 0) return;

  char* ws = (char*)d_ws;
  unsigned short* featT = (unsigned short*)(ws + oFEAT);
  float2* xyb = (float2*)(ws + oXY);
  float4* lwb = (float4*)(ws + oLW);
  float* part = (float*)(ws + oPART);
  unsigned short* qfb  = (unsigned short*)(ws + oQFB);
  unsigned short* wpgT = (unsigned short*)(ws + oWPGT);
  unsigned short* woutT= (unsigned short*)(ws + oWOUT);
  unsigned short* par  = (unsigned short*)(ws + oPAR);
  unsigned short* o2   = par;   // aliased

  k_off<<<250, 384, 0, stream>>>(qf, xyzr, w_off, b_off, xyb, lwb);
  k_prep2<<<9696, 256, 0, stream>>>(feat0, feat1, feat2, feat3, qf, w_pg, w_out,
                                    featT, qfb, wpgT, woutT);

  int mtiles = qpad / 128;
  for (int c = 0; c < NC; ++c) {
    int qbase = c * qcount;
    int qlim  = qbase + qcount;
    k_pgemm_mfma<<<mtiles*256, 256, 0, stream>>>(qfb, wpgT, b_pg, par, qbase, qlim, mtiles);
    k_mix<<<qcount*4, 256, 0, stream>>>(featT, xyb, lwb, par, o2, qbase);
    k_fgemm_mfma<<<mtiles*2*KSP, 256, 0, stream>>>(o2, woutT, part, qbase, qlim, mtiles, KSP);
  }
  k_ln<<<NQ, 256, 0, stream>>>(part, qf, b_out, ln_g, ln_b, (float*)d_out, KSP);
}

// Round 22
// 289.472 us; speedup vs baseline: 1.0212x; 1.0212x over previous
//
#include <hip/hip_runtime.h>
#include <hip/hip_bf16.h>
#include <cstdint>
#include <cstddef>

#define DI __device__ __forceinline__

// ---------- constants ----------
#define NN 500
#define NQ 2000           // B*N
#define GTOT 32768        // G*TOTAL
#define LN_EPS 1e-5f

typedef __attribute__((ext_vector_type(8))) short short8v;
typedef __attribute__((ext_vector_type(4))) float f32x4;
typedef const __attribute__((address_space(1))) void* gp1_t;
typedef __attribute__((address_space(3))) void* lp3_t;

DI unsigned short f2bf(float f){
  unsigned u = __float_as_uint(f);
  return (unsigned short)((u + 0x7fffu + ((u>>16)&1u)) >> 16);
}
DI float bf2f(unsigned short s){ return __uint_as_float(((unsigned)s)<<16); }

DI ushort4 cvt4(float4 a){
  ushort4 r; r.x=f2bf(a.x); r.y=f2bf(a.y); r.z=f2bf(a.z); r.w=f2bf(a.w); return r;
}

// block-wide (256 thr = 4 waves) sum of s, s2
DI void bred256(float& s, float& s2, float* red, int tid){
  #pragma unroll
  for(int off=32; off; off>>=1){
    s  += __shfl_xor(s,  off, 64);
    s2 += __shfl_xor(s2, off, 64);
  }
  int w = tid>>6;
  if((tid&63)==0){ red[w*2]=s; red[w*2+1]=s2; }
  __syncthreads();
  s  = red[0]+red[2]+red[4]+red[6];
  s2 = red[1]+red[3]+red[5]+red[7];
  __syncthreads();
}

// ---------- K1: offset GEMM + sample coords + level softmax (384 thr) ----------
__global__ __launch_bounds__(384) void k_off(const float* __restrict__ qf,
    const float* __restrict__ xyzr, const float* __restrict__ w_off,
    const float* __restrict__ b_off, float2* __restrict__ xyb, float4* __restrict__ lwb){
  __shared__ float qs[8][256];
  __shared__ float os[8][384];
  int q0 = blockIdx.x*8, tid = threadIdx.x;
  for(int idx=tid; idx<2048; idx+=384){
    int qq = idx>>8, k = idx&255;
    qs[qq][k] = qf[(size_t)(q0+qq)*256 + k];
  }
  __syncthreads();
  {
    int j = tid;
    float acc[8];
    #pragma unroll
    for(int i=0;i<8;i++) acc[i]=0.f;
    for(int k=0;k<256;k++){
      float w = w_off[(size_t)k*384 + j];
      #pragma unroll
      for(int qq=0;qq<8;qq++) acc[qq] += qs[qq][k]*w;
    }
    float bb = b_off[j];
    #pragma unroll
    for(int qq=0;qq<8;qq++) os[qq][j] = acc[qq] + bb;
  }
  __syncthreads();
  for(int idx=tid; idx<1024; idx+=384){
    int qq = idx>>7, gp = idx&127;
    int q = q0+qq;
    float4 xr = *(const float4*)&xyzr[(size_t)q*4];
    float rw = exp2f(xr.z - 0.5f*xr.w);
    float rh = exp2f(xr.z + 0.5f*xr.w);
    float sx = xr.x + os[qq][gp*3+0]*rw;
    float sy = xr.y + os[qq][gp*3+1]*rh;
    float lvl = xr.z + os[qq][gp*3+2] - 3.0f;
    float d0=lvl, d1=lvl-1.f, d2=lvl-2.f, d3=lvl-3.f;
    float e0=-0.5f*d0*d0, e1=-0.5f*d1*d1, e2=-0.5f*d2*d2, e3=-0.5f*d3*d3;
    float m = fmaxf(fmaxf(e0,e1),fmaxf(e2,e3));
    float x0=expf(e0-m), x1=expf(e1-m), x2=expf(e2-m), x3=expf(e3-m);
    float inv = 1.f/(x0+x1+x2+x3);
    xyb[(size_t)q*128+gp] = make_float2(sx,sy);
    lwb[(size_t)q*128+gp] = make_float4(x0*inv, x1*inv, x2*inv, x3*inv);
  }
}

// ---------- K-prep2: fused transposes + cvtqf ----------
__global__ __launch_bounds__(256) void k_prep2(
    const float* __restrict__ f0, const float* __restrict__ f1,
    const float* __restrict__ f2, const float* __restrict__ f3,
    const float* __restrict__ qf, const float* __restrict__ w_pg,
    const float* __restrict__ w_out, unsigned short* __restrict__ featT,
    unsigned short* __restrict__ qfb, unsigned short* __restrict__ wpgT,
    unsigned short* __restrict__ woutT){
  __shared__ unsigned short tile[64*68];
  int bid = blockIdx.x, tid = threadIdx.x;

  if(bid < 4096){
    const float* src; unsigned short* dst; int R, C, lb;
    if(bid < 2048){ src=w_pg;  dst=wpgT;  R=256;  C=GTOT; lb=bid; }
    else          { src=w_out; dst=woutT; R=GTOT; C=256;  lb=bid-2048; }
    int ctiles = C >> 6;
    int rt = lb / ctiles, ct = lb % ctiles;
    int r0 = rt<<6, c0 = ct<<6;
    #pragma unroll
    for(int i=0;i<4;i++){
      int idx = tid + i*256;
      int r = idx >> 4, c4 = (idx & 15)*4;
      float4 v = *(const float4*)(src + (size_t)(r0+r)*C + c0 + c4);
      *(ushort4*)(tile + r*68 + c4) = cvt4(v);
    }
    __syncthreads();
    #pragma unroll
    for(int i=0;i<4;i++){
      int idx = tid + i*256;
      int cc = idx >> 4, r4 = (idx & 15)*4;
      ushort4 v;
      v.x = tile[(r4+0)*68 + cc];
      v.y = tile[(r4+1)*68 + cc];
      v.z = tile[(r4+2)*68 + cc];
      v.w = tile[(r4+3)*68 + cc];
      *(ushort4*)(dst + (size_t)(c0+cc)*R + r0 + r4) = v;
    }
  } else if(bid < 9440){
    const float* src; unsigned short* dst; int HW, nb, lb;
    int fb = bid - 4096;
    if(fb < 4000){ src=f0; dst=featT;            HW=16000; nb=250; lb=fb; }
    else if(fb < 5008){ src=f1; dst=featT+16384000; HW=4000; nb=63; lb=fb-4000; }
    else if(fb < 5264){ src=f2; dst=featT+20480000; HW=1000; nb=16; lb=fb-5008; }
    else { src=f3; dst=featT+21504000; HW=260; nb=5; lb=fb-5264; }
    int bg = lb / nb, hb = lb % nb;
    int b = bg >> 2, g = bg & 3;
    const float* s = src + ((size_t)(b*256 + g*64))*HW + hb*64;
    unsigned short* d = dst + (size_t)bg*HW*64 + (size_t)hb*64*64;
    int rem = HW - hb*64;
    #pragma unroll
    for(int i=0;i<4;i++){
      int idx = tid + i*256;
      int c = idx >> 4, h4 = (idx & 15)*4;
      if(h4 < rem){
        float4 v = *(const float4*)(s + (size_t)c*HW + h4);
        *(ushort4*)(tile + c*68 + h4) = cvt4(v);
      }
    }
    __syncthreads();
    #pragma unroll
    for(int i=0;i<4;i++){
      int idx = tid + i*256;
      int hw = idx >> 4, c4 = (idx & 15)*4;
      if(hw < rem){
        ushort4 v;
        v.x = tile[(c4+0)*68 + hw];
        v.y = tile[(c4+1)*68 + hw];
        v.z = tile[(c4+2)*68 + hw];
        v.w = tile[(c4+3)*68 + hw];
        *(ushort4*)(d + (size_t)hw*64 + c4) = v;
      }
    }
  } else {
    int idx = (bid-9440)*256 + tid;
    size_t base = (size_t)idx*8;
    int row = idx >> 5;
    ushort4 lo, hi;
    if(row < NQ){
      float4 a = *(const float4*)(qf + base);
      float4 b = *(const float4*)(qf + base + 4);
      lo = cvt4(a); hi = cvt4(b);
    } else {
      lo.x=lo.y=lo.z=lo.w=0; hi.x=hi.y=hi.z=hi.w=0;
    }
    *(ushort4*)(qfb + base) = lo;
    *(ushort4*)(qfb + base + 4) = hi;
  }
}

// ---------- MFMA helpers ----------
DI f32x4 mfma16(short8v a, short8v b, f32x4 c){
  return __builtin_amdgcn_mfma_f32_16x16x32_bf16(a, b, c, 0, 0, 0);
}

// swizzle for [*][32]-short tiles: 16B chunk c XOR row bits -> bank-balanced b128 reads
DI int swz32(int c, int r){ return c ^ (r&3) ^ ((r>>2)&3); }

// stage a 128x32 bf16 tile into linear LDS via global_load_lds, source pre-swizzled.
DI void stageG32(const unsigned short* __restrict__ g, size_t row0, size_t ldk,
                 size_t k0, unsigned short* lds, int tid){
  int wv = tid>>6;
  #pragma unroll
  for(int i=0;i<2;i++){
    int e = i*256 + tid;          // 16B-chunk index 0..511
    int r = e>>2, c = e&3;
    int cs = swz32(c, r);
    const unsigned short* gp = g + (row0 + (size_t)r)*ldk + k0 + (size_t)cs*8;
    unsigned short* lp = lds + (size_t)(i*256 + wv*64)*8;   // wave-uniform base
    __builtin_amdgcn_global_load_lds((gp1_t)(const void*)gp, (lp3_t)(void*)lp, 16, 0, 0);
  }
}

// read one fragment (row, k-chunk q4) from swizzled [*][32] tile
DI short8v frag32(const unsigned short* lds, int row, int q4){
  return *(const short8v*)(lds + (size_t)row*32 + (size_t)swz32(q4, row)*8);
}

// one BK=32 step for 128x128 tile: 4 A-frags, 4 B-frags, 16 MFMA
DI void mma32(const unsigned short* lsA, const unsigned short* lsB,
              int wm, int wn, int lane, f32x4 acc[4][4]){
  int r15 = lane&15, q4 = lane>>4;
  short8v a[4], b[4];
  #pragma unroll
  for(int i=0;i<4;i++){
    a[i] = frag32(lsA, wm*64 + i*16 + r15, q4);
    b[i] = frag32(lsB, wn*64 + i*16 + r15, q4);
  }
  #pragma unroll
  for(int mi=0;mi<4;mi++)
    #pragma unroll
    for(int ni=0;ni<4;ni++)
      acc[mi][ni] = mfma16(a[mi], b[ni], acc[mi][ni]);
}

// XCD-affinity remap: consecutive logical blocks land on one XCD (nwg % 8 == 0).
DI int xcd_remap(int bid, int nwg){
  return ((bid & 7) * (nwg >> 3)) + (bid >> 3);
}

// ---------- K2: params GEMM via MFMA: par = qfb @ wpgT^T + b_pg ----------
__global__ __launch_bounds__(256, 4) void k_pgemm_mfma(const unsigned short* __restrict__ qfb,
    const unsigned short* __restrict__ wpgT, const float* __restrict__ b_pg,
    unsigned short* __restrict__ par, int qbase, int qlim, int mtiles){
  __shared__ unsigned short pool[16384];     // 32 KB
  int bid = xcd_remap(blockIdx.x, gridDim.x);
  int mt = bid % mtiles, nt = bid / mtiles;
  size_t m0 = (size_t)mt*128, n0 = (size_t)nt*128;
  int tid = threadIdx.x, lane = tid&63, wv = tid>>6;
  int wm = wv>>1, wn = wv&1;
  int r15 = lane&15, q4 = lane>>4;
  f32x4 acc[4][4] = {};
  stageG32(qfb,  qbase+m0, 256, 0, pool, tid);
  stageG32(wpgT, n0,       256, 0, pool + 8192, tid);
  __syncthreads();
  #pragma unroll
  for(int t=0; t<8; t++){
    int co = (t&1)*4096;
    if(t<7){
      int no = ((t&1)^1)*4096;
      stageG32(qfb,  qbase+m0, 256, (size_t)(t+1)*32, pool + no, tid);
      stageG32(wpgT, n0,       256, (size_t)(t+1)*32, pool + 8192 + no, tid);
    }
    mma32(pool + co, pool + 8192 + co, wm, wn, lane, acc);
    __syncthreads();
  }
  // epilogue: stage bf16 result in LDS [128][72], store full 128B rows, two col-halves
  unsigned short* es = pool;
  #pragma unroll
  for(int h=0; h<2; ++h){
    if(h) __syncthreads();
    if(wn == h){
      #pragma unroll
      for(int ni=0; ni<4; ni++){
        float bias = b_pg[(int)n0 + wn*64 + ni*16 + r15];
        #pragma unroll
        for(int mi=0; mi<4; mi++)
          #pragma unroll
          for(int j=0; j<4; j++){
            int row = wm*64 + mi*16 + q4*4 + j;
            es[row*72 + ni*16 + r15] = f2bf(acc[mi][ni][j] + bias);
          }
      }
    }
    __syncthreads();
    #pragma unroll
    for(int i=0;i<4;i++){
      int e = i*256 + tid;              // 1024 chunks of 8 shorts
      int row = e>>3, c8 = (e&7)*8;
      int rl = (int)m0 + row;
      if(qbase + rl < qlim){
        uint4 v = *(const uint4*)(es + row*72 + c8);
        *(uint4*)&par[(size_t)rl*GTOT + n0 + h*64 + c8] = v;
      }
    }
  }
}

// ---------- K4: final GEMM via MFMA, 128x128 tiles, K-split x kspl -> bf16 partials ----------
__global__ __launch_bounds__(256, 4) void k_fgemm_mfma(const unsigned short* __restrict__ Ag,
    const unsigned short* __restrict__ woutT, unsigned short* __restrict__ part,
    int qbase, int qlim, int mtiles, int kspl){
  __shared__ unsigned short pool[16384];
  int bid = xcd_remap(blockIdx.x, gridDim.x);
  int nt = bid & 1;
  int r2 = bid >> 1;
  int mt = r2 % mtiles, ks = r2 / mtiles;
  size_t m0 = (size_t)mt*128, n0 = (size_t)nt*128;
  int tid = threadIdx.x, lane = tid&63, wv = tid>>6;
  int wm = wv>>1, wn = wv&1;
  f32x4 acc[4][4] = {};
  int klen = GTOT / kspl;
  size_t kbase = (size_t)ks*klen;
  int NT = klen >> 5;
  stageG32(Ag,    m0, GTOT, kbase, pool, tid);
  stageG32(woutT, n0, GTOT, kbase, pool + 8192, tid);
  __syncthreads();
  for(int t=0; t<NT; t++){
    int co = (t&1)*4096;
    if(t+1<NT){
      int no = ((t&1)^1)*4096;
      stageG32(Ag,    m0, GTOT, kbase + (size_t)(t+1)*32, pool + no, tid);
      stageG32(woutT, n0, GTOT, kbase + (size_t)(t+1)*32, pool + 8192 + no, tid);
    }
    mma32(pool + co, pool + 8192 + co, wm, wn, lane, acc);
    __syncthreads();
  }
  unsigned short* pp = part + (size_t)ks*NQ*256;
  int r15 = lane&15, q4 = lane>>4;
  #pragma unroll
  for(int mi=0; mi<4; mi++){
    #pragma unroll
    for(int j=0; j<4; j++){
      int rl = (int)m0 + wm*64 + mi*16 + q4*4 + j;
      int q = qbase + rl;
      if(q < qlim){
        #pragma unroll
        for(int ni=0; ni<4; ni++){
          int col = (int)n0 + wn*64 + ni*16 + r15;
          pp[(size_t)q*256 + col] = f2bf(acc[mi][ni][j]);
        }
      }
    }
  }
}

// ---------- K3: sampling + M/S mixing via MFMA + two group-LN+relu -> out2 bf16 ----------
// Merged pool 26624 B. Layout (byte offsets):
//   offW [0,4096)  xs[32][72] [4096,8704)  Ms[64][68] [8704,17408)  Ss[128][36] [17408,26624)
//   o1t[64][40] aliases [0,5120); o2s[128][72] aliases [0,18432) — all clobbers barrier-separated.
__global__ __launch_bounds__(256) void k_mix(const unsigned short* __restrict__ featT,
    const float2* __restrict__ xyb, const float4* __restrict__ lwb,
    const unsigned short* __restrict__ par, unsigned short* __restrict__ out2,
    int qbase){
  __shared__ __align__(16) char pool[26624];
  __shared__ float red[8];
  float* offW = (float*)pool;
  unsigned short* xs  = (unsigned short*)(pool + 4096);
  unsigned short* Ms  = (unsigned short*)(pool + 8704);
  unsigned short* Ss  = (unsigned short*)(pool + 17408);
  unsigned short* o1t = (unsigned short*)pool;   // alias [0,5120)
  unsigned short* o2s = (unsigned short*)pool;   // alias [0,18432)

  int lq = blockIdx.x >> 2, g = blockIdx.x & 3;
  int q = qbase + lq;
  int b = q / NN;
  int bg = b*4 + g;
  int tid = threadIdx.x;
  int lane = tid & 63, wv = tid >> 6;

  const int HH[4] = {100,50,25,13};
  const int WW[4] = {160,80,40,20};
  const float IS[4] = {0.125f, 0.0625f, 0.03125f, 0.015625f};
  const int LO[4] = {0, 16384000, 20480000, 21504000};

  const unsigned short* pb = par + (size_t)lq*GTOT + (size_t)g*8192;
  uint4 mraw0 = *(const uint4*)(pb + tid*8);
  uint4 mraw1 = *(const uint4*)(pb + 2048 + tid*8);
  uint4 sraw0 = *(const uint4*)(pb + 4096 + tid*8);
  uint4 sraw1 = *(const uint4*)(pb + 6144 + tid*8);

  if(tid < 128){
    int p = tid >> 2, l = tid & 3;
    int pi = q*128 + g*32 + p;
    float2 xy = xyb[pi];
    float lw4 = ((const float*)lwb)[(size_t)pi*4 + l];
    int H = HH[l], W = WW[l];
    float px = xy.x*IS[l] - 0.5f;
    float py = xy.y*IS[l] - 0.5f;
    float xf = floorf(px), yf = floorf(py);
    float wx = px - xf, wy = py - yf;
    int x0 = (int)xf, y0 = (int)yf;
    int x1 = x0 + 1, y1 = y0 + 1;
    bool vx0 = (x0>=0)&&(x0<W), vx1 = (x1>=0)&&(x1<W);
    bool vy0 = (y0>=0)&&(y0<H), vy1 = (y1>=0)&&(y1<H);
    int x0c = min(max(x0,0),W-1), x1c = min(max(x1,0),W-1);
    int y0c = min(max(y0,0),H-1), y1c = min(max(y1,0),H-1);
    int baseB = (LO[l] + bg*H*W*64) * 2;      // BYTE offset base
    float* e = offW + tid*8;
    e[0] = __int_as_float(baseB + (y0c*W + x0c)*128);
    e[1] = __int_as_float(baseB + (y0c*W + x1c)*128);
    e[2] = __int_as_float(baseB + (y1c*W + x0c)*128);
    e[3] = __int_as_float(baseB + (y1c*W + x1c)*128);
    e[4] = (1.f-wx)*(1.f-wy)*lw4*(float)(vx0&&vy0);
    e[5] = wx*(1.f-wy)*lw4*(float)(vx1&&vy0);
    e[6] = (1.f-wx)*wy*lw4*(float)(vx0&&vy1);
    e[7] = wx*wy*lw4*(float)(vx1&&vy1);
  }

  {
    int idx0 = tid*8;
    int c0 = idx0>>6, d0 = idx0&63;
    *(uint2*)(Ms + c0*68 + d0)     = make_uint2(mraw0.x, mraw0.y);
    *(uint2*)(Ms + c0*68 + d0 + 4) = make_uint2(mraw0.z, mraw0.w);
    int idx1 = 2048 + tid*8;
    int c1 = idx1>>6, d1 = idx1&63;
    *(uint2*)(Ms + c1*68 + d1)     = make_uint2(mraw1.x, mraw1.y);
    *(uint2*)(Ms + c1*68 + d1 + 4) = make_uint2(mraw1.z, mraw1.w);
    int o0 = idx0>>5, p0 = idx0&31;
    *(uint2*)(Ss + o0*36 + p0)     = make_uint2(sraw0.x, sraw0.y);
    *(uint2*)(Ss + o0*36 + p0 + 4) = make_uint2(sraw0.z, sraw0.w);
    int o1_ = idx1>>5, p1 = idx1&31;
    *(uint2*)(Ss + o1_*36 + p1)     = make_uint2(sraw1.x, sraw1.y);
    *(uint2*)(Ss + o1_*36 + p1 + 4) = make_uint2(sraw1.z, sraw1.w);
  }
  __syncthreads();

  // Phase A: 4-channel gather. quarter-wave (16 lanes) per p; lane cg = channel quad.
  {
    int pg4 = lane >> 4;           // p within group of 4
    int cg  = lane & 15;           // channel quad: channels cg*4..cg*4+3
    const char* fbB = (const char*)featT + cg*8;
    #pragma unroll
    for(int i=0;i<2;i++){
      int p = wv*8 + i*4 + pg4;
      const float* e = offW + p*32;
      f32x4 acc4 = {0.f, 0.f, 0.f, 0.f};
      #pragma unroll
      for(int l=0;l<4;l++){
        int4  ea = *(const int4*)(e + l*8);
        float4 eb = *(const float4*)(e + l*8 + 4);
        uint2 u00 = *(const uint2*)(fbB + ea.x);
        uint2 u01 = *(const uint2*)(fbB + ea.y);
        uint2 u10 = *(const uint2*)(fbB + ea.z);
        uint2 u11 = *(const uint2*)(fbB + ea.w);
        f32x4 v;
        v[0]=__uint_as_float(u00.x<<16); v[1]=__uint_as_float(u00.x&0xffff0000u);
        v[2]=__uint_as_float(u00.y<<16); v[3]=__uint_as_float(u00.y&0xffff0000u);
        acc4 += v * eb.x;
        v[0]=__uint_as_float(u01.x<<16); v[1]=__uint_as_float(u01.x&0xffff0000u);
        v[2]=__uint_as_float(u01.y<<16); v[3]=__uint_as_float(u01.y&0xffff0000u);
        acc4 += v * eb.y;
        v[0]=__uint_as_float(u10.x<<16); v[1]=__uint_as_float(u10.x&0xffff0000u);
        v[2]=__uint_as_float(u10.y<<16); v[3]=__uint_as_float(u10.y&0xffff0000u);
        acc4 += v * eb.z;
        v[0]=__uint_as_float(u11.x<<16); v[1]=__uint_as_float(u11.x&0xffff0000u);
        v[2]=__uint_as_float(u11.y<<16); v[3]=__uint_as_float(u11.y&0xffff0000u);
        acc4 += v * eb.w;
      }
      unsigned w0 = (unsigned)f2bf(acc4[0]) | ((unsigned)f2bf(acc4[1])<<16);
      unsigned w1 = (unsigned)f2bf(acc4[2]) | ((unsigned)f2bf(acc4[3])<<16);
      *(uint2*)(xs + p*72 + cg*4) = make_uint2(w0, w1);
    }
  }
  __syncthreads();

  int r = lane & 15, q4 = lane >> 4;

  // Phase B: out1 = x(32x64) @ M(64x64)
  {
    short8v af00 = *(const short8v*)(xs + r*72 + q4*8);
    short8v af01 = *(const short8v*)(xs + r*72 + 32 + q4*8);
    short8v af10 = *(const short8v*)(xs + (16+r)*72 + q4*8);
    short8v af11 = *(const short8v*)(xs + (16+r)*72 + 32 + q4*8);
    short8v bm0, bm1;
    #pragma unroll
    for(int j=0;j<8;j++){
      bm0[j] = (short)Ms[(8*q4+j)*68 + wv*16 + r];
      bm1[j] = (short)Ms[(32+8*q4+j)*68 + wv*16 + r];
    }
    f32x4 a0 = {}, a1 = {};
    a0 = mfma16(af00, bm0, a0); a0 = mfma16(af01, bm1, a0);
    a1 = mfma16(af10, bm0, a1); a1 = mfma16(af11, bm1, a1);

    float s = 0.f, s2 = 0.f;
    #pragma unroll
    for(int v=0;v<4;v++){ s += a0[v]+a1[v]; s2 += a0[v]*a0[v] + a1[v]*a1[v]; }
    bred256(s, s2, red, tid);   // barrier: all xs/Ms reads complete before o1t writes below
    float mean = s*(1.f/2048.f);
    float var = s2*(1.f/2048.f) - mean*mean;
    float rs = rsqrtf(var + LN_EPS);
    ushort4 st0, st1;
    {
      float f0;
      f0 = (a0[0]-mean)*rs; st0.x = f2bf(f0>0.f?f0:0.f);
      f0 = (a0[1]-mean)*rs; st0.y = f2bf(f0>0.f?f0:0.f);
      f0 = (a0[2]-mean)*rs; st0.z = f2bf(f0>0.f?f0:0.f);
      f0 = (a0[3]-mean)*rs; st0.w = f2bf(f0>0.f?f0:0.f);
      f0 = (a1[0]-mean)*rs; st1.x = f2bf(f0>0.f?f0:0.f);
      f0 = (a1[1]-mean)*rs; st1.y = f2bf(f0>0.f?f0:0.f);
      f0 = (a1[2]-mean)*rs; st1.z = f2bf(f0>0.f?f0:0.f);
      f0 = (a1[3]-mean)*rs; st1.w = f2bf(f0>0.f?f0:0.f);
    }
    *(ushort4*)(o1t + (wv*16+r)*40 + 4*q4)      = st0;   // p = 4q4..+3 (mi=0)
    *(ushort4*)(o1t + (wv*16+r)*40 + 16 + 4*q4) = st1;   // p = 16+4q4..+3 (mi=1)
  }
  __syncthreads();

  // Phase C: out2 = S(128x32) @ out1(32x64)
  {
    short8v sa0, sa1;
    {
      int row0 = (wv*2+0)*16 + r, row1 = (wv*2+1)*16 + r;
      uint2 a = *(const uint2*)(Ss + row0*36 + q4*8);
      uint2 bq = *(const uint2*)(Ss + row0*36 + q4*8 + 4);
      uint4 t0; t0.x=a.x; t0.y=a.y; t0.z=bq.x; t0.w=bq.y;
      sa0 = *(short8v*)&t0;
      a  = *(const uint2*)(Ss + row1*36 + q4*8);
      bq = *(const uint2*)(Ss + row1*36 + q4*8 + 4);
      uint4 t1; t1.x=a.x; t1.y=a.y; t1.z=bq.x; t1.w=bq.y;
      sa1 = *(short8v*)&t1;
    }
    short8v ov0 = *(const short8v*)(o1t + (r)*40 + q4*8);
    short8v ov1 = *(const short8v*)(o1t + (16+r)*40 + q4*8);
    short8v ov2 = *(const short8v*)(o1t + (32+r)*40 + q4*8);
    short8v ov3 = *(const short8v*)(o1t + (48+r)*40 + q4*8);
    f32x4 c2[2][4] = {};
    c2[0][0] = mfma16(sa0, ov0, c2[0][0]); c2[0][1] = mfma16(sa0, ov1, c2[0][1]);
    c2[0][2] = mfma16(sa0, ov2, c2[0][2]); c2[0][3] = mfma16(sa0, ov3, c2[0][3]);
    c2[1][0] = mfma16(sa1, ov0, c2[1][0]); c2[1][1] = mfma16(sa1, ov1, c2[1][1]);
    c2[1][2] = mfma16(sa1, ov2, c2[1][2]); c2[1][3] = mfma16(sa1, ov3, c2[1][3]);

    float s = 0.f, s2 = 0.f;
    #pragma unroll
    for(int m=0;m<2;m++)
      #pragma unroll
      for(int ni=0;ni<4;ni++)
        #pragma unroll
        for(int v=0;v<4;v++){ float x = c2[m][ni][v]; s += x; s2 += x*x; }
    bred256(s, s2, red, tid);   // barrier: all Ss/o1t reads complete before o2s writes
    float mean = s*(1.f/8192.f);
    float var = s2*(1.f/8192.f) - mean*mean;
    float rs = rsqrtf(var + LN_EPS);
    #pragma unroll
    for(int m=0;m<2;m++)
      #pragma unroll
      for(int ni=0;ni<4;ni++)
        #pragma unroll
        for(int v=0;v<4;v++){
          float x = (c2[m][ni][v]-mean)*rs; x = x>0.f ? x : 0.f;
          int o = (wv*2+m)*16 + 4*q4 + v;
          int d = ni*16 + r;
          o2s[o*72 + d] = f2bf(x);
        }
  }
  __syncthreads();

  // coalesced vectorized store: 128 rows x 64 cols as 1024 uint4 chunks
  unsigned short* og = out2 + (size_t)lq*GTOT + (size_t)g*8192;
  #pragma unroll
  for(int i=0;i<4;i++){
    int e = i*256 + tid;
    int row = e>>3, c8 = (e&7)*8;
    uint4 v = *(const uint4*)(o2s + row*72 + c8);
    *(uint4*)(og + row*64 + c8) = v;
  }
}

// ---------- K5: K-split reduce (bf16 partials) + bias + residual + LayerNorm ----------
__global__ __launch_bounds__(256) void k_ln(const unsigned short* __restrict__ part,
    const float* __restrict__ qf, const float* __restrict__ b_out,
    const float* __restrict__ ln_g, const float* __restrict__ ln_b,
    float* __restrict__ out, int kspl){
  __shared__ float red[8];
  int q = blockIdx.x, j = threadIdx.x;
  float s = qf[(size_t)q*256 + j] + b_out[j];
  for(int ks=0; ks<kspl; ks++) s += bf2f(part[((size_t)ks*NQ + q)*256 + j]);
  float a = s, a2 = s*s;
  bred256(a, a2, red, j);
  float mean = a*(1.f/256.f);
  float var = a2*(1.f/256.f) - mean*mean;
  float rs = rsqrtf(var + LN_EPS);
  out[(size_t)q*256 + j] = (s-mean)*rs*ln_g[j] + ln_b[j];
}

// ---------- launch ----------
extern "C" void kernel_launch(void* const* d_in, const int* in_sizes, int n_in,
                              void* d_out, int out_size, void* d_ws, size_t ws_size,
                              hipStream_t stream) {
  const float* feat0 = (const float*)d_in[0];
  const float* feat1 = (const float*)d_in[1];
  const float* feat2 = (const float*)d_in[2];
  const float* feat3 = (const float*)d_in[3];
  const float* qf    = (const float*)d_in[4];
  const float* xyzr  = (const float*)d_in[5];
  const float* w_off = (const float*)d_in[6];
  const float* b_off = (const float*)d_in[7];
  const float* w_pg  = (const float*)d_in[8];
  const float* b_pg  = (const float*)d_in[9];
  const float* w_out = (const float*)d_in[10];
  const float* b_out = (const float*)d_in[11];
  const float* ln_g  = (const float*)d_in[12];
  const float* ln_b  = (const float*)d_in[13];

  // Layout search (part now bf16: KSP*NQ*256*2 bytes).
  int KSP=0, NC=0, qcount=0, qpad=0;
  size_t oFEAT=0,oXY=0,oLW=0,oPART=0,oQFB=0,oWPGT=0,oWOUT=0,oPAR=0;
  {
    const int a_ksp[2] = {32, 16};
    for(int ci=0; ci<2 && NC==0; ci++){
      size_t o = 0;
      auto al = [&](size_t bytes){ size_t r = o; o = (o + bytes + 255) & ~255ull; return r; };
      size_t tFEAT = al(43540480ull);
      size_t tXY   = al((size_t)NQ*128*8);
      size_t tLW   = al((size_t)NQ*128*16);
      size_t tQFB  = al((size_t)2048*256*2);
      size_t tWPGT = al((size_t)GTOT*256*2);
      size_t partBytes = (size_t)a_ksp[ci]*NQ*256*2;
      if(partBytes > o) o = (partBytes + 255) & ~255ull;   // part aliases [0, ...)
      size_t tWOUT = al((size_t)256*GTOT*2);
      size_t tPAR  = al((size_t)2048*GTOT*2);
      if(o <= ws_size){
        KSP=a_ksp[ci]; NC=1; qcount=NQ; qpad=2048;
        oFEAT=tFEAT; oXY=tXY; oLW=tLW; oPART=0; oQFB=tQFB; oWPGT=tWPGT; oWOUT=tWOUT; oPAR=tPAR;
      }
    }
    const int c_nc[3] = {2,4,8};
    for(int ci=0; ci<3 && NC==0; ci++){
      size_t o = 0;
      auto al = [&](size_t bytes){ size_t r = o; o = (o + bytes + 255) & ~255ull; return r; };
      size_t tFEAT = al(43540480ull);
      size_t tXY   = al((size_t)NQ*128*8);
      size_t tLW   = al((size_t)NQ*128*16);
      size_t tPART = al((size_t)16*NQ*256*2);
      size_t tQFB  = al((size_t)2048*256*2);
      size_t tWPGT = al((size_t)GTOT*256*2);
      size_t tWOUT = al((size_t)256*GTOT*2);
      int qc = NQ / c_nc[ci];
      int qp = (qc + 127) & ~127;
      size_t tPAR = al((size_t)qp*GTOT*2);
      if(o <= ws_size){
        KSP=16; NC=c_nc[ci]; qcount=qc; qpad=qp;
        oFEAT=tFEAT; oXY=tXY; oLW=tLW; oPART=tPART; oQFB=tQFB; oWPGT=tWPGT; oWOUT=tWOUT; oPAR=tPAR;
      }
    }
  }
  if(NC == 0) return;

  char* ws = (char*)d_ws;
  unsigned short* featT = (unsigned short*)(ws + oFEAT);
  float2* xyb = (float2*)(ws + oXY);
  float4* lwb = (float4*)(ws + oLW);
  unsigned short* part = (unsigned short*)(ws + oPART);
  unsigned short* qfb  = (unsigned short*)(ws + oQFB);
  unsigned short* wpgT = (unsigned short*)(ws + oWPGT);
  unsigned short* woutT= (unsigned short*)(ws + oWOUT);
  unsigned short* par  = (unsigned short*)(ws + oPAR);
  unsigned short* o2   = par;   // aliased

  k_off<<<250, 384, 0, stream>>>(qf, xyzr, w_off, b_off, xyb, lwb);
  k_prep2<<<9696, 256, 0, stream>>>(feat0, feat1, feat2, feat3, qf, w_pg, w_out,
                                    featT, qfb, wpgT, woutT);

  int mtiles = qpad / 128;
  for (int c = 0; c < NC; ++c) {
    int qbase = c * qcount;
    int qlim  = qbase + qcount;
    k_pgemm_mfma<<<mtiles*256, 256, 0, stream>>>(qfb, wpgT, b_pg, par, qbase, qlim, mtiles);
    k_mix<<<qcount*4, 256, 0, stream>>>(featT, xyb, lwb, par, o2, qbase);
    k_fgemm_mfma<<<mtiles*2*KSP, 256, 0, stream>>>(o2, woutT, part, qbase, qlim, mtiles, KSP);
  }
  k_ln<<<NQ, 256, 0, stream>>>(part, qf, b_out, ln_g, ln_b, (float*)d_out, KSP);
}

// Round 23
// 285.553 us; speedup vs baseline: 1.0352x; 1.0137x over previous
//
#include <hip/hip_runtime.h>
#include <hip/hip_bf16.h>
#include <hip/hip_fp16.h>
#include <cstdint>
#include <cstddef>

#define DI __device__ __forceinline__

// ---------- constants ----------
#define NN 500
#define NQ 2000           // B*N
#define GTOT 32768        // G*TOTAL
#define LN_EPS 1e-5f

typedef __attribute__((ext_vector_type(8))) short short8v;
typedef __attribute__((ext_vector_type(4))) float f32x4;
typedef const __attribute__((address_space(1))) void* gp1_t;
typedef __attribute__((address_space(3))) void* lp3_t;

DI unsigned short f2bf(float f){
  unsigned u = __float_as_uint(f);
  return (unsigned short)((u + 0x7fffu + ((u>>16)&1u)) >> 16);
}
DI float bf2f(unsigned short s){ return __uint_as_float(((unsigned)s)<<16); }

DI ushort4 cvt4(float4 a){
  ushort4 r; r.x=f2bf(a.x); r.y=f2bf(a.y); r.z=f2bf(a.z); r.w=f2bf(a.w); return r;
}
// f32x4 -> 4x f16
DI ushort4 cvt4h(float4 a){
  ushort4 r;
  r.x = __half_as_ushort(__float2half(a.x));
  r.y = __half_as_ushort(__float2half(a.y));
  r.z = __half_as_ushort(__float2half(a.z));
  r.w = __half_as_ushort(__float2half(a.w));
  return r;
}
DI float h2bits(__half2 h){ float f; __builtin_memcpy(&f, &h, 4); return f; }
DI __half2 bits2h2f(float f){ __half2 h; __builtin_memcpy(&h, &f, 4); return h; }
DI __half2 bits2h2u(unsigned u){ __half2 h; __builtin_memcpy(&h, &u, 4); return h; }

// block-wide (256 thr = 4 waves) sum of s, s2
DI void bred256(float& s, float& s2, float* red, int tid){
  #pragma unroll
  for(int off=32; off; off>>=1){
    s  += __shfl_xor(s,  off, 64);
    s2 += __shfl_xor(s2, off, 64);
  }
  int w = tid>>6;
  if((tid&63)==0){ red[w*2]=s; red[w*2+1]=s2; }
  __syncthreads();
  s  = red[0]+red[2]+red[4]+red[6];
  s2 = red[1]+red[3]+red[5]+red[7];
  __syncthreads();
}

// ---------- K1: offset GEMM + sample coords + level softmax (384 thr) ----------
__global__ __launch_bounds__(384) void k_off(const float* __restrict__ qf,
    const float* __restrict__ xyzr, const float* __restrict__ w_off,
    const float* __restrict__ b_off, float2* __restrict__ xyb, float4* __restrict__ lwb){
  __shared__ float qs[8][256];
  __shared__ float os[8][384];
  int q0 = blockIdx.x*8, tid = threadIdx.x;
  for(int idx=tid; idx<2048; idx+=384){
    int qq = idx>>8, k = idx&255;
    qs[qq][k] = qf[(size_t)(q0+qq)*256 + k];
  }
  __syncthreads();
  {
    int j = tid;
    float acc[8];
    #pragma unroll
    for(int i=0;i<8;i++) acc[i]=0.f;
    for(int k=0;k<256;k++){
      float w = w_off[(size_t)k*384 + j];
      #pragma unroll
      for(int qq=0;qq<8;qq++) acc[qq] += qs[qq][k]*w;
    }
    float bb = b_off[j];
    #pragma unroll
    for(int qq=0;qq<8;qq++) os[qq][j] = acc[qq] + bb;
  }
  __syncthreads();
  for(int idx=tid; idx<1024; idx+=384){
    int qq = idx>>7, gp = idx&127;
    int q = q0+qq;
    float4 xr = *(const float4*)&xyzr[(size_t)q*4];
    float rw = exp2f(xr.z - 0.5f*xr.w);
    float rh = exp2f(xr.z + 0.5f*xr.w);
    float sx = xr.x + os[qq][gp*3+0]*rw;
    float sy = xr.y + os[qq][gp*3+1]*rh;
    float lvl = xr.z + os[qq][gp*3+2] - 3.0f;
    float d0=lvl, d1=lvl-1.f, d2=lvl-2.f, d3=lvl-3.f;
    float e0=-0.5f*d0*d0, e1=-0.5f*d1*d1, e2=-0.5f*d2*d2, e3=-0.5f*d3*d3;
    float m = fmaxf(fmaxf(e0,e1),fmaxf(e2,e3));
    float x0=expf(e0-m), x1=expf(e1-m), x2=expf(e2-m), x3=expf(e3-m);
    float inv = 1.f/(x0+x1+x2+x3);
    xyb[(size_t)q*128+gp] = make_float2(sx,sy);
    lwb[(size_t)q*128+gp] = make_float4(x0*inv, x1*inv, x2*inv, x3*inv);
  }
}

// ---------- K-prep2: fused transposes + cvtqf (featT now f16) ----------
__global__ __launch_bounds__(256) void k_prep2(
    const float* __restrict__ f0, const float* __restrict__ f1,
    const float* __restrict__ f2, const float* __restrict__ f3,
    const float* __restrict__ qf, const float* __restrict__ w_pg,
    const float* __restrict__ w_out, unsigned short* __restrict__ featT,
    unsigned short* __restrict__ qfb, unsigned short* __restrict__ wpgT,
    unsigned short* __restrict__ woutT){
  __shared__ unsigned short tile[64*68];
  int bid = blockIdx.x, tid = threadIdx.x;

  if(bid < 4096){
    const float* src; unsigned short* dst; int R, C, lb;
    if(bid < 2048){ src=w_pg;  dst=wpgT;  R=256;  C=GTOT; lb=bid; }
    else          { src=w_out; dst=woutT; R=GTOT; C=256;  lb=bid-2048; }
    int ctiles = C >> 6;
    int rt = lb / ctiles, ct = lb % ctiles;
    int r0 = rt<<6, c0 = ct<<6;
    #pragma unroll
    for(int i=0;i<4;i++){
      int idx = tid + i*256;
      int r = idx >> 4, c4 = (idx & 15)*4;
      float4 v = *(const float4*)(src + (size_t)(r0+r)*C + c0 + c4);
      *(ushort4*)(tile + r*68 + c4) = cvt4(v);
    }
    __syncthreads();
    #pragma unroll
    for(int i=0;i<4;i++){
      int idx = tid + i*256;
      int cc = idx >> 4, r4 = (idx & 15)*4;
      ushort4 v;
      v.x = tile[(r4+0)*68 + cc];
      v.y = tile[(r4+1)*68 + cc];
      v.z = tile[(r4+2)*68 + cc];
      v.w = tile[(r4+3)*68 + cc];
      *(ushort4*)(dst + (size_t)(c0+cc)*R + r0 + r4) = v;
    }
  } else if(bid < 9440){
    const float* src; unsigned short* dst; int HW, nb, lb;
    int fb = bid - 4096;
    if(fb < 4000){ src=f0; dst=featT;            HW=16000; nb=250; lb=fb; }
    else if(fb < 5008){ src=f1; dst=featT+16384000; HW=4000; nb=63; lb=fb-4000; }
    else if(fb < 5264){ src=f2; dst=featT+20480000; HW=1000; nb=16; lb=fb-5008; }
    else { src=f3; dst=featT+21504000; HW=260; nb=5; lb=fb-5264; }
    int bg = lb / nb, hb = lb % nb;
    int b = bg >> 2, g = bg & 3;
    const float* s = src + ((size_t)(b*256 + g*64))*HW + hb*64;
    unsigned short* d = dst + (size_t)bg*HW*64 + (size_t)hb*64*64;
    int rem = HW - hb*64;
    #pragma unroll
    for(int i=0;i<4;i++){
      int idx = tid + i*256;
      int c = idx >> 4, h4 = (idx & 15)*4;
      if(h4 < rem){
        float4 v = *(const float4*)(s + (size_t)c*HW + h4);
        *(ushort4*)(tile + c*68 + h4) = cvt4h(v);     // f16 for pk_fma gather
      }
    }
    __syncthreads();
    #pragma unroll
    for(int i=0;i<4;i++){
      int idx = tid + i*256;
      int hw = idx >> 4, c4 = (idx & 15)*4;
      if(hw < rem){
        ushort4 v;
        v.x = tile[(c4+0)*68 + hw];
        v.y = tile[(c4+1)*68 + hw];
        v.z = tile[(c4+2)*68 + hw];
        v.w = tile[(c4+3)*68 + hw];
        *(ushort4*)(d + (size_t)hw*64 + c4) = v;
      }
    }
  } else {
    int idx = (bid-9440)*256 + tid;
    size_t base = (size_t)idx*8;
    int row = idx >> 5;
    ushort4 lo, hi;
    if(row < NQ){
      float4 a = *(const float4*)(qf + base);
      float4 b = *(const float4*)(qf + base + 4);
      lo = cvt4(a); hi = cvt4(b);
    } else {
      lo.x=lo.y=lo.z=lo.w=0; hi.x=hi.y=hi.z=hi.w=0;
    }
    *(ushort4*)(qfb + base) = lo;
    *(ushort4*)(qfb + base + 4) = hi;
  }
}

// ---------- MFMA helpers ----------
DI f32x4 mfma16(short8v a, short8v b, f32x4 c){
  return __builtin_amdgcn_mfma_f32_16x16x32_bf16(a, b, c, 0, 0, 0);
}

// swizzle for [*][32]-short tiles: 16B chunk c XOR row bits -> bank-balanced b128 reads
DI int swz32(int c, int r){ return c ^ (r&3) ^ ((r>>2)&3); }

// stage a 128x32 bf16 tile into linear LDS via global_load_lds, source pre-swizzled.
DI void stageG32(const unsigned short* __restrict__ g, size_t row0, size_t ldk,
                 size_t k0, unsigned short* lds, int tid){
  int wv = tid>>6;
  #pragma unroll
  for(int i=0;i<2;i++){
    int e = i*256 + tid;          // 16B-chunk index 0..511
    int r = e>>2, c = e&3;
    int cs = swz32(c, r);
    const unsigned short* gp = g + (row0 + (size_t)r)*ldk + k0 + (size_t)cs*8;
    unsigned short* lp = lds + (size_t)(i*256 + wv*64)*8;   // wave-uniform base
    __builtin_amdgcn_global_load_lds((gp1_t)(const void*)gp, (lp3_t)(void*)lp, 16, 0, 0);
  }
}

// read one fragment (row, k-chunk q4) from swizzled [*][32] tile
DI short8v frag32(const unsigned short* lds, int row, int q4){
  return *(const short8v*)(lds + (size_t)row*32 + (size_t)swz32(q4, row)*8);
}

// one BK=32 step for 128x128 tile: 4 A-frags, 4 B-frags, 16 MFMA
DI void mma32(const unsigned short* lsA, const unsigned short* lsB,
              int wm, int wn, int lane, f32x4 acc[4][4]){
  int r15 = lane&15, q4 = lane>>4;
  short8v a[4], b[4];
  #pragma unroll
  for(int i=0;i<4;i++){
    a[i] = frag32(lsA, wm*64 + i*16 + r15, q4);
    b[i] = frag32(lsB, wn*64 + i*16 + r15, q4);
  }
  #pragma unroll
  for(int mi=0;mi<4;mi++)
    #pragma unroll
    for(int ni=0;ni<4;ni++)
      acc[mi][ni] = mfma16(a[mi], b[ni], acc[mi][ni]);
}

// XCD-affinity remap: consecutive logical blocks land on one XCD (nwg % 8 == 0).
DI int xcd_remap(int bid, int nwg){
  return ((bid & 7) * (nwg >> 3)) + (bid >> 3);
}

// ---------- K2: params GEMM via MFMA: par = qfb @ wpgT^T + b_pg ----------
__global__ __launch_bounds__(256, 4) void k_pgemm_mfma(const unsigned short* __restrict__ qfb,
    const unsigned short* __restrict__ wpgT, const float* __restrict__ b_pg,
    unsigned short* __restrict__ par, int qbase, int qlim, int mtiles){
  __shared__ unsigned short pool[16384];     // 32 KB
  int bid = xcd_remap(blockIdx.x, gridDim.x);
  int mt = bid % mtiles, nt = bid / mtiles;
  size_t m0 = (size_t)mt*128, n0 = (size_t)nt*128;
  int tid = threadIdx.x, lane = tid&63, wv = tid>>6;
  int wm = wv>>1, wn = wv&1;
  int r15 = lane&15, q4 = lane>>4;
  f32x4 acc[4][4] = {};
  stageG32(qfb,  qbase+m0, 256, 0, pool, tid);
  stageG32(wpgT, n0,       256, 0, pool + 8192, tid);
  __syncthreads();
  #pragma unroll
  for(int t=0; t<8; t++){
    int co = (t&1)*4096;
    if(t<7){
      int no = ((t&1)^1)*4096;
      stageG32(qfb,  qbase+m0, 256, (size_t)(t+1)*32, pool + no, tid);
      stageG32(wpgT, n0,       256, (size_t)(t+1)*32, pool + 8192 + no, tid);
    }
    mma32(pool + co, pool + 8192 + co, wm, wn, lane, acc);
    __syncthreads();
  }
  // epilogue: stage bf16 result in LDS [128][72], store full 128B rows, two col-halves
  unsigned short* es = pool;
  #pragma unroll
  for(int h=0; h<2; ++h){
    if(h) __syncthreads();
    if(wn == h){
      #pragma unroll
      for(int ni=0; ni<4; ni++){
        float bias = b_pg[(int)n0 + wn*64 + ni*16 + r15];
        #pragma unroll
        for(int mi=0; mi<4; mi++)
          #pragma unroll
          for(int j=0; j<4; j++){
            int row = wm*64 + mi*16 + q4*4 + j;
            es[row*72 + ni*16 + r15] = f2bf(acc[mi][ni][j] + bias);
          }
      }
    }
    __syncthreads();
    #pragma unroll
    for(int i=0;i<4;i++){
      int e = i*256 + tid;              // 1024 chunks of 8 shorts
      int row = e>>3, c8 = (e&7)*8;
      int rl = (int)m0 + row;
      if(qbase + rl < qlim){
        uint4 v = *(const uint4*)(es + row*72 + c8);
        *(uint4*)&par[(size_t)rl*GTOT + n0 + h*64 + c8] = v;
      }
    }
  }
}

// ---------- K4: final GEMM via MFMA, 128x128 tiles, K-split x kspl -> bf16 partials ----------
__global__ __launch_bounds__(256, 4) void k_fgemm_mfma(const unsigned short* __restrict__ Ag,
    const unsigned short* __restrict__ woutT, unsigned short* __restrict__ part,
    int qbase, int qlim, int mtiles, int kspl){
  __shared__ unsigned short pool[16384];
  int bid = xcd_remap(blockIdx.x, gridDim.x);
  int nt = bid & 1;
  int r2 = bid >> 1;
  int mt = r2 % mtiles, ks = r2 / mtiles;
  size_t m0 = (size_t)mt*128, n0 = (size_t)nt*128;
  int tid = threadIdx.x, lane = tid&63, wv = tid>>6;
  int wm = wv>>1, wn = wv&1;
  f32x4 acc[4][4] = {};
  int klen = GTOT / kspl;
  size_t kbase = (size_t)ks*klen;
  int NT = klen >> 5;
  stageG32(Ag,    m0, GTOT, kbase, pool, tid);
  stageG32(woutT, n0, GTOT, kbase, pool + 8192, tid);
  __syncthreads();
  for(int t=0; t<NT; t++){
    int co = (t&1)*4096;
    if(t+1<NT){
      int no = ((t&1)^1)*4096;
      stageG32(Ag,    m0, GTOT, kbase + (size_t)(t+1)*32, pool + no, tid);
      stageG32(woutT, n0, GTOT, kbase + (size_t)(t+1)*32, pool + 8192 + no, tid);
    }
    mma32(pool + co, pool + 8192 + co, wm, wn, lane, acc);
    __syncthreads();
  }
  unsigned short* pp = part + (size_t)ks*NQ*256;
  int r15 = lane&15, q4 = lane>>4;
  #pragma unroll
  for(int mi=0; mi<4; mi++){
    #pragma unroll
    for(int j=0; j<4; j++){
      int rl = (int)m0 + wm*64 + mi*16 + q4*4 + j;
      int q = qbase + rl;
      if(q < qlim){
        #pragma unroll
        for(int ni=0; ni<4; ni++){
          int col = (int)n0 + wn*64 + ni*16 + r15;
          pp[(size_t)q*256 + col] = f2bf(acc[mi][ni][j]);
        }
      }
    }
  }
}

// ---------- K3: sampling + M/S mixing via MFMA + two group-LN+relu -> out2 bf16 ----------
// Merged pool 26624 B. Layout (byte offsets):
//   offW [0,4096)  xs[32][72] [4096,8704)  Ms[64][68] [8704,17408)  Ss[128][36] [17408,26624)
//   o1t[64][40] aliases [0,5120); o2s[128][72] aliases [0,18432) — all clobbers barrier-separated.
__global__ __launch_bounds__(256) void k_mix(const unsigned short* __restrict__ featT,
    const float2* __restrict__ xyb, const float4* __restrict__ lwb,
    const unsigned short* __restrict__ par, unsigned short* __restrict__ out2,
    int qbase){
  __shared__ __align__(16) char pool[26624];
  __shared__ float red[8];
  float* offW = (float*)pool;
  unsigned short* xs  = (unsigned short*)(pool + 4096);
  unsigned short* Ms  = (unsigned short*)(pool + 8704);
  unsigned short* Ss  = (unsigned short*)(pool + 17408);
  unsigned short* o1t = (unsigned short*)pool;   // alias [0,5120)
  unsigned short* o2s = (unsigned short*)pool;   // alias [0,18432)

  int lq = blockIdx.x >> 2, g = blockIdx.x & 3;
  int q = qbase + lq;
  int b = q / NN;
  int bg = b*4 + g;
  int tid = threadIdx.x;
  int lane = tid & 63, wv = tid >> 6;

  const int HH[4] = {100,50,25,13};
  const int WW[4] = {160,80,40,20};
  const float IS[4] = {0.125f, 0.0625f, 0.03125f, 0.015625f};
  const int LO[4] = {0, 16384000, 20480000, 21504000};

  const unsigned short* pb = par + (size_t)lq*GTOT + (size_t)g*8192;
  uint4 mraw0 = *(const uint4*)(pb + tid*8);
  uint4 mraw1 = *(const uint4*)(pb + 2048 + tid*8);
  uint4 sraw0 = *(const uint4*)(pb + 4096 + tid*8);
  uint4 sraw1 = *(const uint4*)(pb + 6144 + tid*8);

  if(tid < 128){
    int p = tid >> 2, l = tid & 3;
    int pi = q*128 + g*32 + p;
    float2 xy = xyb[pi];
    float lw4 = ((const float*)lwb)[(size_t)pi*4 + l];
    int H = HH[l], W = WW[l];
    float px = xy.x*IS[l] - 0.5f;
    float py = xy.y*IS[l] - 0.5f;
    float xf = floorf(px), yf = floorf(py);
    float wx = px - xf, wy = py - yf;
    int x0 = (int)xf, y0 = (int)yf;
    int x1 = x0 + 1, y1 = y0 + 1;
    bool vx0 = (x0>=0)&&(x0<W), vx1 = (x1>=0)&&(x1<W);
    bool vy0 = (y0>=0)&&(y0<H), vy1 = (y1>=0)&&(y1<H);
    int x0c = min(max(x0,0),W-1), x1c = min(max(x1,0),W-1);
    int y0c = min(max(y0,0),H-1), y1c = min(max(y1,0),H-1);
    int baseB = (LO[l] + bg*H*W*64) * 2;      // BYTE offset base
    float* e = offW + tid*8;
    e[0] = __int_as_float(baseB + (y0c*W + x0c)*128);
    e[1] = __int_as_float(baseB + (y0c*W + x1c)*128);
    e[2] = __int_as_float(baseB + (y1c*W + x0c)*128);
    e[3] = __int_as_float(baseB + (y1c*W + x1c)*128);
    __half2 h0 = __float2half2_rn((1.f-wx)*(1.f-wy)*lw4*(float)(vx0&&vy0));
    __half2 h1 = __float2half2_rn(wx*(1.f-wy)*lw4*(float)(vx1&&vy0));
    __half2 h2 = __float2half2_rn((1.f-wx)*wy*lw4*(float)(vx0&&vy1));
    __half2 h3 = __float2half2_rn(wx*wy*lw4*(float)(vx1&&vy1));
    e[4] = h2bits(h0);
    e[5] = h2bits(h1);
    e[6] = h2bits(h2);
    e[7] = h2bits(h3);
  }

  {
    int idx0 = tid*8;
    int c0 = idx0>>6, d0 = idx0&63;
    *(uint2*)(Ms + c0*68 + d0)     = make_uint2(mraw0.x, mraw0.y);
    *(uint2*)(Ms + c0*68 + d0 + 4) = make_uint2(mraw0.z, mraw0.w);
    int idx1 = 2048 + tid*8;
    int c1 = idx1>>6, d1 = idx1&63;
    *(uint2*)(Ms + c1*68 + d1)     = make_uint2(mraw1.x, mraw1.y);
    *(uint2*)(Ms + c1*68 + d1 + 4) = make_uint2(mraw1.z, mraw1.w);
    int o0 = idx0>>5, p0 = idx0&31;
    *(uint2*)(Ss + o0*36 + p0)     = make_uint2(sraw0.x, sraw0.y);
    *(uint2*)(Ss + o0*36 + p0 + 4) = make_uint2(sraw0.z, sraw0.w);
    int o1_ = idx1>>5, p1 = idx1&31;
    *(uint2*)(Ss + o1_*36 + p1)     = make_uint2(sraw1.x, sraw1.y);
    *(uint2*)(Ss + o1_*36 + p1 + 4) = make_uint2(sraw1.z, sraw1.w);
  }
  __syncthreads();

  // Phase A: 4-channel f16 gather. quarter-wave per p; 2 v_pk_fma_f16 per corner, no unpack.
  {
    int pg4 = lane >> 4;           // p within group of 4
    int cg  = lane & 15;           // channel quad: channels cg*4..cg*4+3
    const char* fbB = (const char*)featT + cg*8;
    #pragma unroll
    for(int i=0;i<2;i++){
      int p = wv*8 + i*4 + pg4;
      const float* e = offW + p*32;
      __half2 a01 = __float2half2_rn(0.f), a23 = __float2half2_rn(0.f);
      #pragma unroll
      for(int l=0;l<4;l++){
        int4  ea = *(const int4*)(e + l*8);
        float4 eb = *(const float4*)(e + l*8 + 4);
        uint2 u00 = *(const uint2*)(fbB + ea.x);
        uint2 u01 = *(const uint2*)(fbB + ea.y);
        uint2 u10 = *(const uint2*)(fbB + ea.z);
        uint2 u11 = *(const uint2*)(fbB + ea.w);
        __half2 w0 = bits2h2f(eb.x), w1 = bits2h2f(eb.y);
        __half2 w2 = bits2h2f(eb.z), w3 = bits2h2f(eb.w);
        a01 = __hfma2(bits2h2u(u00.x), w0, a01);
        a23 = __hfma2(bits2h2u(u00.y), w0, a23);
        a01 = __hfma2(bits2h2u(u01.x), w1, a01);
        a23 = __hfma2(bits2h2u(u01.y), w1, a23);
        a01 = __hfma2(bits2h2u(u10.x), w2, a01);
        a23 = __hfma2(bits2h2u(u10.y), w2, a23);
        a01 = __hfma2(bits2h2u(u11.x), w3, a01);
        a23 = __hfma2(bits2h2u(u11.y), w3, a23);
      }
      float g0 = __half2float(__low2half(a01));
      float g1 = __half2float(__high2half(a01));
      float g2 = __half2float(__low2half(a23));
      float g3 = __half2float(__high2half(a23));
      unsigned w0b = (unsigned)f2bf(g0) | ((unsigned)f2bf(g1)<<16);
      unsigned w1b = (unsigned)f2bf(g2) | ((unsigned)f2bf(g3)<<16);
      *(uint2*)(xs + p*72 + cg*4) = make_uint2(w0b, w1b);
    }
  }
  __syncthreads();

  int r = lane & 15, q4 = lane >> 4;

  // Phase B: out1 = x(32x64) @ M(64x64)
  {
    short8v af00 = *(const short8v*)(xs + r*72 + q4*8);
    short8v af01 = *(const short8v*)(xs + r*72 + 32 + q4*8);
    short8v af10 = *(const short8v*)(xs + (16+r)*72 + q4*8);
    short8v af11 = *(const short8v*)(xs + (16+r)*72 + 32 + q4*8);
    short8v bm0, bm1;
    #pragma unroll
    for(int j=0;j<8;j++){
      bm0[j] = (short)Ms[(8*q4+j)*68 + wv*16 + r];
      bm1[j] = (short)Ms[(32+8*q4+j)*68 + wv*16 + r];
    }
    f32x4 a0 = {}, a1 = {};
    a0 = mfma16(af00, bm0, a0); a0 = mfma16(af01, bm1, a0);
    a1 = mfma16(af10, bm0, a1); a1 = mfma16(af11, bm1, a1);

    float s = 0.f, s2 = 0.f;
    #pragma unroll
    for(int v=0;v<4;v++){ s += a0[v]+a1[v]; s2 += a0[v]*a0[v] + a1[v]*a1[v]; }
    bred256(s, s2, red, tid);   // barrier: all xs/Ms reads complete before o1t writes below
    float mean = s*(1.f/2048.f);
    float var = s2*(1.f/2048.f) - mean*mean;
    float rs = rsqrtf(var + LN_EPS);
    ushort4 st0, st1;
    {
      float f0;
      f0 = (a0[0]-mean)*rs; st0.x = f2bf(f0>0.f?f0:0.f);
      f0 = (a0[1]-mean)*rs; st0.y = f2bf(f0>0.f?f0:0.f);
      f0 = (a0[2]-mean)*rs; st0.z = f2bf(f0>0.f?f0:0.f);
      f0 = (a0[3]-mean)*rs; st0.w = f2bf(f0>0.f?f0:0.f);
      f0 = (a1[0]-mean)*rs; st1.x = f2bf(f0>0.f?f0:0.f);
      f0 = (a1[1]-mean)*rs; st1.y = f2bf(f0>0.f?f0:0.f);
      f0 = (a1[2]-mean)*rs; st1.z = f2bf(f0>0.f?f0:0.f);
      f0 = (a1[3]-mean)*rs; st1.w = f2bf(f0>0.f?f0:0.f);
    }
    *(ushort4*)(o1t + (wv*16+r)*40 + 4*q4)      = st0;   // p = 4q4..+3 (mi=0)
    *(ushort4*)(o1t + (wv*16+r)*40 + 16 + 4*q4) = st1;   // p = 16+4q4..+3 (mi=1)
  }
  __syncthreads();

  // Phase C: out2 = S(128x32) @ out1(32x64)
  {
    short8v sa0, sa1;
    {
      int row0 = (wv*2+0)*16 + r, row1 = (wv*2+1)*16 + r;
      uint2 a = *(const uint2*)(Ss + row0*36 + q4*8);
      uint2 bq = *(const uint2*)(Ss + row0*36 + q4*8 + 4);
      uint4 t0; t0.x=a.x; t0.y=a.y; t0.z=bq.x; t0.w=bq.y;
      sa0 = *(short8v*)&t0;
      a  = *(const uint2*)(Ss + row1*36 + q4*8);
      bq = *(const uint2*)(Ss + row1*36 + q4*8 + 4);
      uint4 t1; t1.x=a.x; t1.y=a.y; t1.z=bq.x; t1.w=bq.y;
      sa1 = *(short8v*)&t1;
    }
    short8v ov0 = *(const short8v*)(o1t + (r)*40 + q4*8);
    short8v ov1 = *(const short8v*)(o1t + (16+r)*40 + q4*8);
    short8v ov2 = *(const short8v*)(o1t + (32+r)*40 + q4*8);
    short8v ov3 = *(const short8v*)(o1t + (48+r)*40 + q4*8);
    f32x4 c2[2][4] = {};
    c2[0][0] = mfma16(sa0, ov0, c2[0][0]); c2[0][1] = mfma16(sa0, ov1, c2[0][1]);
    c2[0][2] = mfma16(sa0, ov2, c2[0][2]); c2[0][3] = mfma16(sa0, ov3, c2[0][3]);
    c2[1][0] = mfma16(sa1, ov0, c2[1][0]); c2[1][1] = mfma16(sa1, ov1, c2[1][1]);
    c2[1][2] = mfma16(sa1, ov2, c2[1][2]); c2[1][3] = mfma16(sa1, ov3, c2[1][3]);

    float s = 0.f, s2 = 0.f;
    #pragma unroll
    for(int m=0;m<2;m++)
      #pragma unroll
      for(int ni=0;ni<4;ni++)
        #pragma unroll
        for(int v=0;v<4;v++){ float x = c2[m][ni][v]; s += x; s2 += x*x; }
    bred256(s, s2, red, tid);   // barrier: all Ss/o1t reads complete before o2s writes
    float mean = s*(1.f/8192.f);
    float var = s2*(1.f/8192.f) - mean*mean;
    float rs = rsqrtf(var + LN_EPS);
    #pragma unroll
    for(int m=0;m<2;m++)
      #pragma unroll
      for(int ni=0;ni<4;ni++)
        #pragma unroll
        for(int v=0;v<4;v++){
          float x = (c2[m][ni][v]-mean)*rs; x = x>0.f ? x : 0.f;
          int o = (wv*2+m)*16 + 4*q4 + v;
          int d = ni*16 + r;
          o2s[o*72 + d] = f2bf(x);
        }
  }
  __syncthreads();

  // coalesced vectorized store: 128 rows x 64 cols as 1024 uint4 chunks
  unsigned short* og = out2 + (size_t)lq*GTOT + (size_t)g*8192;
  #pragma unroll
  for(int i=0;i<4;i++){
    int e = i*256 + tid;
    int row = e>>3, c8 = (e&7)*8;
    uint4 v = *(const uint4*)(o2s + row*72 + c8);
    *(uint4*)(og + row*64 + c8) = v;
  }
}

// ---------- K5: K-split reduce (bf16 partials) + bias + residual + LayerNorm ----------
__global__ __launch_bounds__(256) void k_ln(const unsigned short* __restrict__ part,
    const float* __restrict__ qf, const float* __restrict__ b_out,
    const float* __restrict__ ln_g, const float* __restrict__ ln_b,
    float* __restrict__ out, int kspl){
  __shared__ float red[8];
  int q = blockIdx.x, j = threadIdx.x;
  float s = qf[(size_t)q*256 + j] + b_out[j];
  for(int ks=0; ks<kspl; ks++) s += bf2f(part[((size_t)ks*NQ + q)*256 + j]);
  float a = s, a2 = s*s;
  bred256(a, a2, red, j);
  float mean = a*(1.f/256.f);
  float var = a2*(1.f/256.f) - mean*mean;
  float rs = rsqrtf(var + LN_EPS);
  out[(size_t)q*256 + j] = (s-mean)*rs*ln_g[j] + ln_b[j];
}

// ---------- launch ----------
extern "C" void kernel_launch(void* const* d_in, const int* in_sizes, int n_in,
                              void* d_out, int out_size, void* d_ws, size_t ws_size,
                              hipStream_t stream) {
  const float* feat0 = (const float*)d_in[0];
  const float* feat1 = (const float*)d_in[1];
  const float* feat2 = (const float*)d_in[2];
  const float* feat3 = (const float*)d_in[3];
  const float* qf    = (const float*)d_in[4];
  const float* xyzr  = (const float*)d_in[5];
  const float* w_off = (const float*)d_in[6];
  const float* b_off = (const float*)d_in[7];
  const float* w_pg  = (const float*)d_in[8];
  const float* b_pg  = (const float*)d_in[9];
  const float* w_out = (const float*)d_in[10];
  const float* b_out = (const float*)d_in[11];
  const float* ln_g  = (const float*)d_in[12];
  const float* ln_b  = (const float*)d_in[13];

  // Layout search (part bf16: KSP*NQ*256*2 bytes).
  int KSP=0, NC=0, qcount=0, qpad=0;
  size_t oFEAT=0,oXY=0,oLW=0,oPART=0,oQFB=0,oWPGT=0,oWOUT=0,oPAR=0;
  {
    const int a_ksp[2] = {32, 16};
    for(int ci=0; ci<2 && NC==0; ci++){
      size_t o = 0;
      auto al = [&](size_t bytes){ size_t r = o; o = (o + bytes + 255) & ~255ull; return r; };
      size_t tFEAT = al(43540480ull);
      size_t tXY   = al((size_t)NQ*128*8);
      size_t tLW   = al((size_t)NQ*128*16);
      size_t tQFB  = al((size_t)2048*256*2);
      size_t tWPGT = al((size_t)GTOT*256*2);
      size_t partBytes = (size_t)a_ksp[ci]*NQ*256*2;
      if(partBytes > o) o = (partBytes + 255) & ~255ull;   // part aliases [0, ...)
      size_t tWOUT = al((size_t)256*GTOT*2);
      size_t tPAR  = al((size_t)2048*GTOT*2);
      if(o <= ws_size){
        KSP=a_ksp[ci]; NC=1; qcount=NQ; qpad=2048;
        oFEAT=tFEAT; oXY=tXY; oLW=tLW; oPART=0; oQFB=tQFB; oWPGT=tWPGT; oWOUT=tWOUT; oPAR=tPAR;
      }
    }
    const int c_nc[3] = {2,4,8};
    for(int ci=0; ci<3 && NC==0; ci++){
      size_t o = 0;
      auto al = [&](size_t bytes){ size_t r = o; o = (o + bytes + 255) & ~255ull; return r; };
      size_t tFEAT = al(43540480ull);
      size_t tXY   = al((size_t)NQ*128*8);
      size_t tLW   = al((size_t)NQ*128*16);
      size_t tPART = al((size_t)16*NQ*256*2);
      size_t tQFB  = al((size_t)2048*256*2);
      size_t tWPGT = al((size_t)GTOT*256*2);
      size_t tWOUT = al((size_t)256*GTOT*2);
      int qc = NQ / c_nc[ci];
      int qp = (qc + 127) & ~127;
      size_t tPAR = al((size_t)qp*GTOT*2);
      if(o <= ws_size){
        KSP=16; NC=c_nc[ci]; qcount=qc; qpad=qp;
        oFEAT=tFEAT; oXY=tXY; oLW=tLW; oPART=tPART; oQFB=tQFB; oWPGT=tWPGT; oWOUT=tWOUT; oPAR=tPAR;
      }
    }
  }
  if(NC == 0) return;

  char* ws = (char*)d_ws;
  unsigned short* featT = (unsigned short*)(ws + oFEAT);
  float2* xyb = (float2*)(ws + oXY);
  float4* lwb = (float4*)(ws + oLW);
  unsigned short* part = (unsigned short*)(ws + oPART);
  unsigned short* qfb  = (unsigned short*)(ws + oQFB);
  unsigned short* wpgT = (unsigned short*)(ws + oWPGT);
  unsigned short* woutT= (unsigned short*)(ws + oWOUT);
  unsigned short* par  = (unsigned short*)(ws + oPAR);
  unsigned short* o2   = par;   // aliased

  k_off<<<250, 384, 0, stream>>>(qf, xyzr, w_off, b_off, xyb, lwb);
  k_prep2<<<9696, 256, 0, stream>>>(feat0, feat1, feat2, feat3, qf, w_pg, w_out,
                                    featT, qfb, wpgT, woutT);

  int mtiles = qpad / 128;
  for (int c = 0; c < NC; ++c) {
    int qbase = c * qcount;
    int qlim  = qbase + qcount;
    k_pgemm_mfma<<<mtiles*256, 256, 0, stream>>>(qfb, wpgT, b_pg, par, qbase, qlim, mtiles);
    k_mix<<<qcount*4, 256, 0, stream>>>(featT, xyb, lwb, par, o2, qbase);
    k_fgemm_mfma<<<mtiles*2*KSP, 256, 0, stream>>>(o2, woutT, part, qbase, qlim, mtiles, KSP);
  }
  k_ln<<<NQ, 256, 0, stream>>>(part, qf, b_out, ln_g, ln_b, (float*)d_out, KSP);
}